// Round 1
// baseline (338.109 us; speedup 1.0000x reference)
//
#include <hip/hip_runtime.h>

#define NPTS 8192
#define NB 4
#define CH 64
#define KNN 16
#define CAP2 128          // survivors per query (expected ~22-30; P(>128) ~ 1e-30)
#define SLACK 4e-3f       // > 2*eps of bf16 hi/lo MFMA distance approx (eps ~ 7e-4)

using bf16x8 = __attribute__((ext_vector_type(8))) __bf16;
using us8    = __attribute__((ext_vector_type(8))) unsigned short;
using f32x4  = __attribute__((ext_vector_type(4))) float;

__device__ __forceinline__ float bf2f(unsigned short u) {
    return __uint_as_float(((unsigned)u) << 16);
}
__device__ __forceinline__ unsigned short f2bf(float f) {
    unsigned u = __float_as_uint(f);
    u += 0x7fffu + ((u >> 16) & 1u);
    return (unsigned short)(u >> 16);
}

// split 8 f32 into hi/lo bf16 fragments: x = hi + lo to ~16 extra mantissa bits
__device__ __forceinline__ void split8(const float* x, bf16x8& hi, bf16x8& lo) {
    us8 h, l;
#pragma unroll
    for (int j = 0; j < 8; ++j) {
        const unsigned short hb = f2bf(x[j]);
        h[j] = hb;
        l[j] = f2bf(x[j] - bf2f(hb));
    }
    hi = __builtin_bit_cast(bf16x8, h);
    lo = __builtin_bit_cast(bf16x8, l);
}

// lexicographic (d,i) compare: true if (dB,iB) < (dA,iA)
__device__ __forceinline__ bool lex_lt(float dB, int iB, float dA, int iA) {
    return (dB < dA) || ((dB == dA) && (iB < iA));
}

// ---------------- Kernel 0: pack {x,y,z,sq} + MFMA B-fragments -----------------------
// B-fragment k-plan (K=32, slots 0..13 used, 16x16x32 layout: col=lane&15, k=(lane>>4)*8+j):
//   k0-2:  (-2c)_hi   k3-5: (-2c)_lo   k6-8: (-2c)_hi   k9-11: (-2c)_lo
//   k12: sq_hi  k13: sq_lo  k14-31: zero (A supplies zeros there)
// Paired with A (query):  k0-5: q_hi,q_hi  k6-11: q_lo,q_lo  k12,13: 1.0
//  => D = (qh+ql)·(-2c_h + -2c_l) + sq_c  =  |c|^2 - 2 q·c   (err ~7e-4 abs)
__global__ __launch_bounds__(256) void pack_kernel(const float* __restrict__ pts,
                                                   float4* __restrict__ pts4,
                                                   uint4* __restrict__ bfrag) {
    const int i = blockIdx.x * 256 + threadIdx.x;   // 0..32767
    const float x = pts[i * 3 + 0];
    const float y = pts[i * 3 + 1];
    const float z = pts[i * 3 + 2];
    const float sq = (x * x + y * y) + z * z;       // reference-path formula
    pts4[i] = make_float4(x, y, z, sq);

    const float sx = -2.f * x, sy = -2.f * y, sz = -2.f * z;
    const unsigned short shx = f2bf(sx), shy = f2bf(sy), shz = f2bf(sz);
    const unsigned short slx = f2bf(sx - bf2f(shx));
    const unsigned short sly = f2bf(sy - bf2f(shy));
    const unsigned short slz = f2bf(sz - bf2f(shz));
    const unsigned short sqh = f2bf(sq), sql = f2bf(sq - bf2f(sqh));

    const int b = i >> 13, n = i & (NPTS - 1);
    const int tile = n >> 4, cw = n & 15;
    uint4* base = bfrag + ((size_t)(b * 512 + tile)) * 32;

    unsigned short g0[8], g1[8];
    g0[0] = shx; g0[1] = shy; g0[2] = shz; g0[3] = slx;
    g0[4] = sly; g0[5] = slz; g0[6] = shx; g0[7] = shy;   // k0..7
    g1[0] = shz; g1[1] = slx; g1[2] = sly; g1[3] = slz;
    g1[4] = sqh; g1[5] = sql; g1[6] = 0;   g1[7] = 0;     // k8..15
    base[cw]      = *(const uint4*)g0;
    base[16 + cw] = *(const uint4*)g1;
}

// A-fragment for one query point, k-group g = lane>>4
__device__ __forceinline__ bf16x8 make_afrag(const float4 qp, const int g) {
    const unsigned short hx = f2bf(qp.x), hy = f2bf(qp.y), hz = f2bf(qp.z);
    const unsigned short lx = f2bf(qp.x - bf2f(hx));
    const unsigned short ly = f2bf(qp.y - bf2f(hy));
    const unsigned short lz = f2bf(qp.z - bf2f(hz));
    us8 u;
#pragma unroll
    for (int j = 0; j < 8; ++j) u[j] = 0;
    if (g == 0) {
        u[0] = hx; u[1] = hy; u[2] = hz; u[3] = hx;
        u[4] = hy; u[5] = hz; u[6] = lx; u[7] = ly;       // k0..7
    } else if (g == 1) {
        u[0] = lz; u[1] = lx; u[2] = ly; u[3] = lz;
        u[4] = 0x3f80u; u[5] = 0x3f80u;                   // 1.0 * sq_hi/lo, k8..15
    }
    return __builtin_bit_cast(bf16x8, u);
}

// ---------------- Kernel 1: MFMA KNN ------------------------------------------------
// Block = 4 waves = 64 consecutive queries of one batch.
// Wave w: query-group qgrp=w>>1 (32 queries = 2 MFMA row-sets), candidate half chalf=w&1.
// Pass A: e-minima over 32 streams/query -> U = 16th-smallest stream-min (upper bound
// on exact 16-NN distance, rank argument). Pass B: admit e<=U+SLACK via LDS atomics.
// Epilogue: exact f32 distances (formula identical to proven kernel) + lex-(d,idx) rank.
__global__ __launch_bounds__(256) void knn_mfma_kernel(const float4* __restrict__ pts4,
                                                       const uint4* __restrict__ bfrag,
                                                       int* __restrict__ idx_out) {
    __shared__ float s_minv[64][33];        // [query][stream], +1 pad
    __shared__ float s_U[64];
    __shared__ int   s_cnt[64];
    __shared__ int   s_surv[64][CAP2];
    __shared__ float s_rd[4][CAP2];
    __shared__ int   s_ri[4][CAP2];

    const int tid  = threadIdx.x;
    const int w    = tid >> 6, lane = tid & 63;
    const int qgrp = w >> 1,  chalf = w & 1;
    const int r    = lane & 15, g = lane >> 4;
    const int qbase = blockIdx.x * 64;               // global query id (= b*8192 + n0)
    const int b = qbase >> 13, n0 = qbase & (NPTS - 1);
    const float4* pb = pts4 + (size_t)b * NPTS;

    // A-fragments: 2 query sets of 16 (M rows = queries)
    const bf16x8 af0 = make_afrag(pb[n0 + qgrp * 32 + r], g);
    const bf16x8 af1 = make_afrag(pb[n0 + qgrp * 32 + 16 + r], g);

    // B pointer: lanes 32-63 duplicate lanes 0-31 (their A elems are zero -> harmless)
    const uint4* bp = bfrag + ((size_t)b * 512 + (size_t)chalf * 256) * 32 + (lane & 31);
    const f32x4 zero4 = {0.f, 0.f, 0.f, 0.f};

    // ---- Pass A: stream minima of e = |c|^2 - 2 q.c ----
    float m0[4], m1[4];
#pragma unroll
    for (int reg = 0; reg < 4; ++reg) { m0[reg] = 3.4e38f; m1[reg] = 3.4e38f; }
    uint4 nb = bp[0];
#pragma unroll 4
    for (int t = 0; t < 256; ++t) {
        const bf16x8 bw = __builtin_bit_cast(bf16x8, nb);
        nb = bp[min(t + 1, 255) * 32];
        const f32x4 a0 = __builtin_amdgcn_mfma_f32_16x16x32_bf16(af0, bw, zero4, 0, 0, 0);
        const f32x4 a1 = __builtin_amdgcn_mfma_f32_16x16x32_bf16(af1, bw, zero4, 0, 0, 0);
#pragma unroll
        for (int reg = 0; reg < 4; ++reg) {
            m0[reg] = fminf(m0[reg], a0[reg]);
            m1[reg] = fminf(m1[reg], a1[reg]);
        }
    }
    // C/D layout: col(lane&15)=candidate-class, row(g*4+reg)=query within set.
    // stream id = chalf*16 + candidate-class.
#pragma unroll
    for (int reg = 0; reg < 4; ++reg) {
        s_minv[qgrp * 32 + g * 4 + reg][chalf * 16 + r] = m0[reg];
        s_minv[qgrp * 32 + 16 + g * 4 + reg][chalf * 16 + r] = m1[reg];
    }
    if (tid < 64) s_cnt[tid] = 0;
    __syncthreads();                                  // B1

    // ---- U select: 16th smallest (rank 15) of 32 stream minima per query ----
    {
        const int q = tid & 63, qt = tid >> 6;        // 4 threads/query, 8 streams each
        float v32[32];
#pragma unroll
        for (int s = 0; s < 32; ++s) v32[s] = s_minv[q][s];
        for (int k = 0; k < 8; ++k) {
            const int s = qt * 8 + k;
            const float v = s_minv[q][s];
            int rk = 0;
#pragma unroll
            for (int s2 = 0; s2 < 32; ++s2)
                rk += (v32[s2] < v || (v32[s2] == v && s2 < s)) ? 1 : 0;
            if (rk == 15) s_U[q] = v;                 // exactly one (value,stream) wins
        }
    }
    __syncthreads();                                  // B2

    // ---- Pass B: gated admission ----
    float U0[4], U1[4];
#pragma unroll
    for (int reg = 0; reg < 4; ++reg) {
        U0[reg] = s_U[qgrp * 32 + g * 4 + reg] + SLACK;
        U1[reg] = s_U[qgrp * 32 + 16 + g * 4 + reg] + SLACK;
    }
    nb = bp[0];
#pragma unroll 2
    for (int t = 0; t < 256; ++t) {
        const bf16x8 bw = __builtin_bit_cast(bf16x8, nb);
        nb = bp[min(t + 1, 255) * 32];
        const f32x4 a0 = __builtin_amdgcn_mfma_f32_16x16x32_bf16(af0, bw, zero4, 0, 0, 0);
        const f32x4 a1 = __builtin_amdgcn_mfma_f32_16x16x32_bf16(af1, bw, zero4, 0, 0, 0);
        const bool h0 = (a0[0] <= U0[0]) | (a0[1] <= U0[1]) | (a0[2] <= U0[2]) | (a0[3] <= U0[3]);
        const bool h1 = (a1[0] <= U1[0]) | (a1[1] <= U1[1]) | (a1[2] <= U1[2]) | (a1[3] <= U1[3]);
        if (h0) {                                     // per-lane rare (~4%)
#pragma unroll
            for (int reg = 0; reg < 4; ++reg)
                if (a0[reg] <= U0[reg]) {
                    const int cand = chalf * 4096 + t * 16 + r;
                    const int pos = atomicAdd(&s_cnt[qgrp * 32 + g * 4 + reg], 1);
                    if (pos < CAP2) s_surv[qgrp * 32 + g * 4 + reg][pos] = cand;
                }
        }
        if (h1) {
#pragma unroll
            for (int reg = 0; reg < 4; ++reg)
                if (a1[reg] <= U1[reg]) {
                    const int cand = chalf * 4096 + t * 16 + r;
                    const int pos = atomicAdd(&s_cnt[qgrp * 32 + 16 + g * 4 + reg], 1);
                    if (pos < CAP2) s_surv[qgrp * 32 + 16 + g * 4 + reg][pos] = cand;
                }
        }
    }
    __syncthreads();                                  // B3

    // ---- Epilogue: exact distances + lex rank (verbatim semantics of proven kernel) --
    for (int qi = 0; qi < 16; ++qi) {
        const int q = w * 16 + qi;
        const int n = min(s_cnt[q], CAP2);
        const float4 qp = pb[n0 + q];
        float d1 = 3.4e38f, d2 = 3.4e38f;
        int i1 = -1, i2 = -1;
        if (lane < n) {
            i1 = s_surv[q][lane];
            const float4 v = pb[i1];
            float dot = qp.x * v.x;
            dot = fmaf(qp.y, v.y, dot);
            dot = fmaf(qp.z, v.z, dot);
            d1 = fmaf(dot, -2.0f, qp.w + v.w);        // identical rounding to reference path
        }
        if (64 + lane < n) {
            i2 = s_surv[q][64 + lane];
            const float4 v = pb[i2];
            float dot = qp.x * v.x;
            dot = fmaf(qp.y, v.y, dot);
            dot = fmaf(qp.z, v.z, dot);
            d2 = fmaf(dot, -2.0f, qp.w + v.w);
        }
        s_rd[w][lane] = d1;      s_ri[w][lane] = i1;
        s_rd[w][64 + lane] = d2; s_ri[w][64 + lane] = i2;
        asm volatile("s_waitcnt lgkmcnt(0)" ::: "memory");   // in-wave LDS producer/consumer
        __builtin_amdgcn_wave_barrier();
        int r1 = 0, r2 = 0;
        for (int k = 0; k < n; ++k) {
            const float dk = s_rd[w][k];
            const int   ik = s_ri[w][k];
            r1 += lex_lt(dk, ik, d1, i1) ? 1 : 0;
            r2 += lex_lt(dk, ik, d2, i2) ? 1 : 0;
        }
        if (lane < n && r1 < KNN)      idx_out[(size_t)(qbase + q) * KNN + r1] = i1;
        if (64 + lane < n && r2 < KNN) idx_out[(size_t)(qbase + q) * KNN + r2] = i2;
        __builtin_amdgcn_wave_barrier();              // scratch WAR across queries (in-wave)
    }
}

// ---------------- Kernel 2: MFMA agg — one wave per point, hi/lo bf16 (r11-proven) ----
#define MIDP 132   // s_mid leading-dim pad: 128 -> 132 breaks bank-aligned row stride
__global__ __launch_bounds__(256) void agg_kernel(
    const float* __restrict__ pts,
    const float* __restrict__ feat,
    const float* __restrict__ w_geom,
    const float* __restrict__ g1, const float* __restrict__ b1,
    const float* __restrict__ m1, const float* __restrict__ v1,
    const float* __restrict__ w_sem,
    const float* __restrict__ g2, const float* __restrict__ b2,
    const float* __restrict__ m2, const float* __restrict__ v2,
    const float* __restrict__ w_fuse,
    const float* __restrict__ g3, const float* __restrict__ b3,
    const float* __restrict__ m3, const float* __restrict__ v3,
    const int* __restrict__ knn_idx,
    float* __restrict__ outp) {

    __shared__ alignas(16) unsigned short s_wsemB[8192];    // 16 frags x 64 lanes x 8 bf16
    __shared__ alignas(16) unsigned short s_wfuseB[8192];
    __shared__ float s_wg[6][64];
    __shared__ float s_s1[64], s_b1[64], s_s2[64], s_b2[64], s_s3[64], s_b3[64];
    __shared__ alignas(16) float s_mid[4][16][MIDP];
    __shared__ float s_pm[4][4][64];
    __shared__ alignas(16) float s_ctrf[4][64];
    __shared__ float s_gd[4][16][4];
    __shared__ int   s_nidx[4][16];
    __shared__ float s_ctrp[4][4];

    const int tid = threadIdx.x;
    const int w = tid >> 6, lane = tid & 63;
    const int r = lane & 15, qd = lane >> 4;

    for (int e = tid; e < 1024; e += 256) {          // e = (kc*4+n0)*64 + ln
        const int ln = e & 63;
        const int o = ((e >> 6) & 3) * 16 + (ln & 15);
        const int c = (e >> 8) * 32 + (ln >> 4) * 8;
        unsigned short ts[8], tf[8];
#pragma unroll
        for (int j = 0; j < 8; ++j) {
            ts[j] = f2bf(w_sem [o * 128 + c + j]);
            tf[j] = f2bf(w_fuse[o * 128 + c + j]);
        }
        *(uint4*)&s_wsemB [e * 8] = *(uint4*)ts;
        *(uint4*)&s_wfuseB[e * 8] = *(uint4*)tf;
    }
    for (int e = tid; e < 384; e += 256) {
        const int c = e >> 6, o = e & 63;
        s_wg[c][o] = w_geom[o * 6 + c];
    }
    if (tid < 64) {
        float s;
        s = g1[tid] / sqrtf(v1[tid] + 1e-5f);
        s_s1[tid] = s; s_b1[tid] = b1[tid] - m1[tid] * s;
        s = g2[tid] / sqrtf(v2[tid] + 1e-5f);
        s_s2[tid] = s; s_b2[tid] = b2[tid] - m2[tid] * s;
        s = g3[tid] / sqrtf(v3[tid] + 1e-5f);
        s_s3[tid] = s; s_b3[tid] = b3[tid] - m3[tid] * s;
    }
    __syncthreads();

    const f32x4 zero = {0.f, 0.f, 0.f, 0.f};

    for (int i = 0; i < 4; ++i) {
        const int pv = blockIdx.x * 16 + w * 4 + i;
        const int b = pv >> 13, n = pv & (NPTS - 1);
        const long pbase = (long)b * NPTS + n;

        if (lane < 16) s_nidx[w][lane] = knn_idx[pbase * KNN + lane];
        s_ctrf[w][lane] = feat[pbase * CH + lane];
        if (lane < 3) s_ctrp[w][lane] = pts[pbase * 3 + lane];
        __syncthreads();                                       // B1

        if (lane < 16) {
            const long nb = (long)b * NPTS + s_nidx[w][lane];
            s_gd[w][lane][0] = pts[nb * 3 + 0] - s_ctrp[w][0];
            s_gd[w][lane][1] = pts[nb * 3 + 1] - s_ctrp[w][1];
            s_gd[w][lane][2] = pts[nb * 3 + 2] - s_ctrp[w][2];
        }

        bf16x8 ah[4], al[4];
        {
            float xs[8];
#pragma unroll
            for (int kc = 0; kc < 2; ++kc) {
#pragma unroll
                for (int j = 0; j < 8; ++j) xs[j] = s_ctrf[w][kc * 32 + qd * 8 + j];
                split8(xs, ah[kc], al[kc]);
            }
            const long nb = (long)b * NPTS + s_nidx[w][r];
            const float* fp = feat + nb * CH;
#pragma unroll
            for (int kc = 0; kc < 2; ++kc) {
                const int base = kc * 32 + qd * 8;
                const float4 v0 = *(const float4*)(fp + base);
                const float4 v1 = *(const float4*)(fp + base + 4);
                xs[0] = v0.x - s_ctrf[w][base + 0];
                xs[1] = v0.y - s_ctrf[w][base + 1];
                xs[2] = v0.z - s_ctrf[w][base + 2];
                xs[3] = v0.w - s_ctrf[w][base + 3];
                xs[4] = v1.x - s_ctrf[w][base + 4];
                xs[5] = v1.y - s_ctrf[w][base + 5];
                xs[6] = v1.z - s_ctrf[w][base + 6];
                xs[7] = v1.w - s_ctrf[w][base + 7];
                split8(xs, ah[2 + kc], al[2 + kc]);
            }
        }
        f32x4 acc[4] = {zero, zero, zero, zero};
#pragma unroll
        for (int kc = 0; kc < 4; ++kc) {
#pragma unroll
            for (int n0 = 0; n0 < 4; ++n0) {
                const bf16x8 bw = *(const bf16x8*)&s_wsemB[((kc * 4 + n0) * 64 + lane) * 8];
                acc[n0] = __builtin_amdgcn_mfma_f32_16x16x32_bf16(ah[kc], bw, acc[n0], 0, 0, 0);
                acc[n0] = __builtin_amdgcn_mfma_f32_16x16x32_bf16(al[kc], bw, acc[n0], 0, 0, 0);
            }
        }
#pragma unroll
        for (int n0 = 0; n0 < 4; ++n0) {
            const int nn = n0 * 16 + r;
            const float sv = s_s2[nn], bv = s_b2[nn];
#pragma unroll
            for (int reg = 0; reg < 4; ++reg) {
                s_mid[w][qd * 4 + reg][64 + nn] = fmaxf(fmaf(acc[n0][reg], sv, bv), 0.f);
            }
        }
        __syncthreads();                                       // B2 (s_gd ready)

        {
            const int o = lane;
            float cg = s_ctrp[w][0] * s_wg[0][o];
            cg = fmaf(s_ctrp[w][1], s_wg[1][o], cg);
            cg = fmaf(s_ctrp[w][2], s_wg[2][o], cg);
            const float s1o = s_s1[o], b1o = s_b1[o];
#pragma unroll
            for (int r2 = 0; r2 < 16; ++r2) {
                float g = cg;
                g = fmaf(s_gd[w][r2][0], s_wg[3][o], g);
                g = fmaf(s_gd[w][r2][1], s_wg[4][o], g);
                g = fmaf(s_gd[w][r2][2], s_wg[5][o], g);
                s_mid[w][r2][o] = fmaxf(fmaf(g, s1o, b1o), 0.f);
            }
        }
        __syncthreads();                                       // B3 (mid complete)

        bf16x8 fh[4], fl[4];
        {
            float xs[8];
#pragma unroll
            for (int kc = 0; kc < 4; ++kc) {
                const float* mp = &s_mid[w][r][kc * 32 + qd * 8];
#pragma unroll
                for (int j = 0; j < 8; ++j) xs[j] = mp[j];
                split8(xs, fh[kc], fl[kc]);
            }
        }
        f32x4 acc2[4] = {zero, zero, zero, zero};
#pragma unroll
        for (int kc = 0; kc < 4; ++kc) {
#pragma unroll
            for (int n0 = 0; n0 < 4; ++n0) {
                const bf16x8 bw = *(const bf16x8*)&s_wfuseB[((kc * 4 + n0) * 64 + lane) * 8];
                acc2[n0] = __builtin_amdgcn_mfma_f32_16x16x32_bf16(fh[kc], bw, acc2[n0], 0, 0, 0);
                acc2[n0] = __builtin_amdgcn_mfma_f32_16x16x32_bf16(fl[kc], bw, acc2[n0], 0, 0, 0);
            }
        }
#pragma unroll
        for (int n0 = 0; n0 < 4; ++n0) {
            const int nn = n0 * 16 + r;
            const float sv = s_s3[nn], bv = s_b3[nn];
            float mx = 0.f;   // relu outputs >= 0
#pragma unroll
            for (int reg = 0; reg < 4; ++reg)
                mx = fmaxf(mx, fmaxf(fmaf(acc2[n0][reg], sv, bv), 0.f));
            s_pm[w][qd][nn] = mx;
        }
        __syncthreads();                                       // B4
        {
            const int o = lane;
            const float rv = fmaxf(fmaxf(s_pm[w][0][o], s_pm[w][1][o]),
                                   fmaxf(s_pm[w][2][o], s_pm[w][3][o]));
            outp[pbase * CH + o] = rv;
        }
        __syncthreads();                                       // B5 (WAR across iters)
    }
}

extern "C" void kernel_launch(void* const* d_in, const int* in_sizes, int n_in,
                              void* d_out, int out_size, void* d_ws, size_t ws_size,
                              hipStream_t stream) {
    (void)in_sizes; (void)n_in; (void)out_size; (void)ws_size;
    const float* pts    = (const float*)d_in[0];
    const float* feat   = (const float*)d_in[1];
    const float* w_geom = (const float*)d_in[2];
    const float* g1     = (const float*)d_in[3];
    const float* b1     = (const float*)d_in[4];
    const float* m1     = (const float*)d_in[5];
    const float* v1     = (const float*)d_in[6];
    const float* w_sem  = (const float*)d_in[7];
    const float* g2     = (const float*)d_in[8];
    const float* b2     = (const float*)d_in[9];
    const float* m2     = (const float*)d_in[10];
    const float* v2     = (const float*)d_in[11];
    const float* w_fuse = (const float*)d_in[12];
    const float* g3     = (const float*)d_in[13];
    const float* b3     = (const float*)d_in[14];
    const float* m3     = (const float*)d_in[15];
    const float* v3     = (const float*)d_in[16];

    int*    idx_final = (int*)d_ws;                             // 2 MB @ 0
    uint4*  bfrag     = (uint4*)((char*)d_ws + (2ull << 20));   // 1 MB @ 2MB
    float4* pts4      = (float4*)((char*)d_ws + (4ull << 20));  // 512 KB @ 4MB

    pack_kernel<<<dim3(NB * NPTS / 256), dim3(256), 0, stream>>>(pts, pts4, bfrag);
    knn_mfma_kernel<<<dim3(NB * NPTS / 64), dim3(256), 0, stream>>>(pts4, bfrag, idx_final);

    agg_kernel<<<dim3(2048), dim3(256), 0, stream>>>(
        pts, feat, w_geom, g1, b1, m1, v1, w_sem, g2, b2, m2, v2,
        w_fuse, g3, b3, m3, v3, idx_final, (float*)d_out);
}

// Round 2
// 317.073 us; speedup vs baseline: 1.0663x; 1.0663x over previous
//
#include <hip/hip_runtime.h>

#define NPTS 8192
#define NB 4
#define CH 64
#define KNN 16
#define CAP2 128          // survivors per query (expected ~20-40; round-1 passed with looser U at 128)
#define SLACK 4e-3f       // > 2*eps of bf16 hi/lo MFMA distance approx (eps ~ 5e-4)
#define MNVP 129          // s_minv pad: 129 % 32 = 1 -> conflict-free column reads

using bf16x8 = __attribute__((ext_vector_type(8))) __bf16;
using us8    = __attribute__((ext_vector_type(8))) unsigned short;
using f32x4  = __attribute__((ext_vector_type(4))) float;
using f32x16 = __attribute__((ext_vector_type(16))) float;

__device__ __forceinline__ float bf2f(unsigned short u) {
    return __uint_as_float(((unsigned)u) << 16);
}
__device__ __forceinline__ unsigned short f2bf(float f) {
    unsigned u = __float_as_uint(f);
    u += 0x7fffu + ((u >> 16) & 1u);
    return (unsigned short)(u >> 16);
}

// split 8 f32 into hi/lo bf16 fragments: x = hi + lo to ~16 extra mantissa bits
__device__ __forceinline__ void split8(const float* x, bf16x8& hi, bf16x8& lo) {
    us8 h, l;
#pragma unroll
    for (int j = 0; j < 8; ++j) {
        const unsigned short hb = f2bf(x[j]);
        h[j] = hb;
        l[j] = f2bf(x[j] - bf2f(hb));
    }
    hi = __builtin_bit_cast(bf16x8, h);
    lo = __builtin_bit_cast(bf16x8, l);
}

// lexicographic (d,i) compare: true if (dB,iB) < (dA,iA)
__device__ __forceinline__ bool lex_lt(float dB, int iB, float dA, int iA) {
    return (dB < dA) || ((dB == dA) && (iB < iA));
}

// ---------------- Kernel 0: pack {x,y,z,sq} + 32x32x16 MFMA B-fragments --------------
// K=16 plan (14 used slots), B layout: col=lane&31 (candidate), k=(lane>>5)*8+j.
//   kh=0 (k0..7):  (-2c)h.xyz, (-2c)l.xyz, (-2c)h.xy
//   kh=1 (k8..15): (-2c)h.z... see g1; k12=sq_hi, k13=sq_lo, k14,15 = 0
// Paired with A (query, row=lane&31, k=(lane>>5)*8+j):
//   kh=0: qh.xyz, qh.xyz, ql.xy    kh=1: ql.z, ql.xyz, 1, 1, 0, 0
//  => D = (qh+ql)·((-2c)h+(-2c)l) + sq_c  =  |c|^2 - 2 q·c   (err ~5e-4 abs)
__global__ __launch_bounds__(256) void pack_kernel(const float* __restrict__ pts,
                                                   float4* __restrict__ pts4,
                                                   uint4* __restrict__ bfrag) {
    const int i = blockIdx.x * 256 + threadIdx.x;   // 0..32767
    const float x = pts[i * 3 + 0];
    const float y = pts[i * 3 + 1];
    const float z = pts[i * 3 + 2];
    const float sq = (x * x + y * y) + z * z;       // reference-path formula
    pts4[i] = make_float4(x, y, z, sq);

    const float sx = -2.f * x, sy = -2.f * y, sz = -2.f * z;
    const unsigned short shx = f2bf(sx), shy = f2bf(sy), shz = f2bf(sz);
    const unsigned short slx = f2bf(sx - bf2f(shx));
    const unsigned short sly = f2bf(sy - bf2f(shy));
    const unsigned short slz = f2bf(sz - bf2f(shz));
    const unsigned short sqh = f2bf(sq), sql = f2bf(sq - bf2f(sqh));

    const int b = i >> 13, n = i & (NPTS - 1);
    const int tile = n >> 5, col = n & 31;
    uint4* base = bfrag + ((size_t)(b * 256 + tile)) * 64;

    unsigned short g0[8], g1[8];
    g0[0] = shx; g0[1] = shy; g0[2] = shz; g0[3] = slx;
    g0[4] = sly; g0[5] = slz; g0[6] = shx; g0[7] = shy;   // k0..7
    g1[0] = shz; g1[1] = slx; g1[2] = sly; g1[3] = slz;
    g1[4] = sqh; g1[5] = sql; g1[6] = 0;   g1[7] = 0;     // k8..15
    base[col]      = *(const uint4*)g0;
    base[32 + col] = *(const uint4*)g1;
}

// A-fragment for one query point, k-half kh = lane>>5 (proven k-plan from round-1)
__device__ __forceinline__ bf16x8 make_afrag(const float4 qp, const int kh) {
    const unsigned short hx = f2bf(qp.x), hy = f2bf(qp.y), hz = f2bf(qp.z);
    const unsigned short lx = f2bf(qp.x - bf2f(hx));
    const unsigned short ly = f2bf(qp.y - bf2f(hy));
    const unsigned short lz = f2bf(qp.z - bf2f(hz));
    us8 u;
#pragma unroll
    for (int j = 0; j < 8; ++j) u[j] = 0;
    if (kh == 0) {
        u[0] = hx; u[1] = hy; u[2] = hz; u[3] = hx;
        u[4] = hy; u[5] = hz; u[6] = lx; u[7] = ly;       // k0..7
    } else {
        u[0] = lz; u[1] = lx; u[2] = ly; u[3] = lz;
        u[4] = 0x3f80u; u[5] = 0x3f80u;                   // 1.0 * sq_hi/lo, k8..15
    }
    return __builtin_bit_cast(bf16x8, u);
}

// ---------------- Kernel 1: MFMA KNN (32x32x16, candidate-quartered waves) -----------
// Block = 4 waves = 64 queries of one batch. Wave w covers candidate tiles
// [w*64, w*64+64) (2048 candidates). Pass A: per-wave stream minima (32 cand-classes
// x 4 waves = 128 streams/query), pairwise-combined to 64; U = rank-15 of 64 stream
// minima (proven broadcast-rank pattern). Pass B: admit e <= U+SLACK via LDS atomics.
// Epilogue: exact f32 distances (byte-identical formula) + lex-(d,idx) rank.
__global__ __launch_bounds__(256) void knn_mfma_kernel(const float4* __restrict__ pts4,
                                                       const uint4* __restrict__ bfrag,
                                                       int* __restrict__ idx_out) {
    __shared__ float s_minv[64][MNVP];      // [query][stream 0..127]
    __shared__ float s_U[64];
    __shared__ int   s_cnt[64];
    __shared__ int   s_surv[64][CAP2];
    __shared__ float s_rd[4][CAP2];
    __shared__ int   s_ri[4][CAP2];

    const int tid  = threadIdx.x;
    const int w    = tid >> 6, lane = tid & 63;
    const int col  = lane & 31, hi = lane >> 5;
    const int qbase = blockIdx.x * 64;               // global query id (= b*8192 + n0)
    const int b = qbase >> 13, n0 = qbase & (NPTS - 1);
    const float4* pb = pts4 + (size_t)b * NPTS;

    // A-fragments: rows = queries. Set0 = n0..n0+31, set1 = n0+32..n0+63.
    const bf16x8 af0 = make_afrag(pb[n0 + col], hi);
    const bf16x8 af1 = make_afrag(pb[n0 + 32 + col], hi);

    // per-lane B pointer for this wave's 64 tiles (1 KB/tile, 16 B/lane)
    const uint4* bpl = bfrag + ((size_t)(b * 256 + w * 64)) * 64 + lane;
    const f32x16 zero16 = {0.f, 0.f, 0.f, 0.f, 0.f, 0.f, 0.f, 0.f,
                           0.f, 0.f, 0.f, 0.f, 0.f, 0.f, 0.f, 0.f};

    // ---- Pass A: stream minima of e = |c|^2 - 2 q.c, 4-deep prefetch ring ----
    float m0[16], m1[16];
#pragma unroll
    for (int r = 0; r < 16; ++r) { m0[r] = 3.4e38f; m1[r] = 3.4e38f; }

    uint4 pf0 = bpl[0 * 64], pf1 = bpl[1 * 64], pf2 = bpl[2 * 64], pf3 = bpl[3 * 64];

#define STEP_A(PF, KOFF)                                                              \
    {                                                                                 \
        const bf16x8 bw = __builtin_bit_cast(bf16x8, PF);                             \
        if (tt < 15) PF = bpl[(tb + 4 + KOFF) * 64];                                  \
        const f32x16 a0 = __builtin_amdgcn_mfma_f32_32x32x16_bf16(af0, bw, zero16, 0, 0, 0); \
        const f32x16 a1 = __builtin_amdgcn_mfma_f32_32x32x16_bf16(af1, bw, zero16, 0, 0, 0); \
        _Pragma("unroll")                                                             \
        for (int r = 0; r < 16; ++r) {                                                \
            m0[r] = fminf(m0[r], a0[r]);                                              \
            m1[r] = fminf(m1[r], a1[r]);                                              \
        }                                                                             \
    }

    for (int tt = 0; tt < 16; ++tt) {
        const int tb = tt * 4;
        STEP_A(pf0, 0)
        STEP_A(pf1, 1)
        STEP_A(pf2, 2)
        STEP_A(pf3, 3)
    }
#undef STEP_A

    // C/D layout (verified): col=lane&31 (cand-class), row=(r&3)+8*(r>>2)+4*hi (query).
    // stream id = w*32 + col.
#pragma unroll
    for (int r = 0; r < 16; ++r) {
        const int q0 = (r & 3) + 8 * (r >> 2) + 4 * hi;
        s_minv[q0][w * 32 + col]      = m0[r];
        s_minv[32 + q0][w * 32 + col] = m1[r];
    }
    if (tid < 64) s_cnt[tid] = 0;
    __syncthreads();                                  // B1 (all 128 streams written)

    // ---- combine 128 -> 64 streams (pairwise min over disjoint candidate sets) ----
    for (int e = tid; e < 64 * 64; e += 256) {
        const int q = e >> 6, j = e & 63;
        s_minv[q][j] = fminf(s_minv[q][j], s_minv[q][64 + j]);
    }
    __syncthreads();                                  // B2

    // ---- U select: rank-15 (16th smallest) of 64 stream minima per query ----
    for (int qi = 0; qi < 16; ++qi) {
        const int q = w * 16 + qi;
        const float v = s_minv[q][lane];
        int rk = 0;
        for (int j = 0; j < 64; ++j) {
            const float vv = s_minv[q][j];
            rk += ((vv < v) || (vv == v && j < lane)) ? 1 : 0;
        }
        if (rk == 15) s_U[q] = v;                     // exactly one (value,stream) wins
    }
    __syncthreads();                                  // B3

    // ---- Pass B: gated admission ----
    float U0[16], U1[16];
#pragma unroll
    for (int r = 0; r < 16; ++r) {
        const int q0 = (r & 3) + 8 * (r >> 2) + 4 * hi;
        U0[r] = s_U[q0] + SLACK;
        U1[r] = s_U[32 + q0] + SLACK;
    }

    pf0 = bpl[0 * 64]; pf1 = bpl[1 * 64]; pf2 = bpl[2 * 64]; pf3 = bpl[3 * 64];

#define STEP_B(PF, KOFF)                                                              \
    {                                                                                 \
        const bf16x8 bw = __builtin_bit_cast(bf16x8, PF);                             \
        if (tt < 15) PF = bpl[(tb + 4 + KOFF) * 64];                                  \
        const f32x16 a0 = __builtin_amdgcn_mfma_f32_32x32x16_bf16(af0, bw, zero16, 0, 0, 0); \
        const f32x16 a1 = __builtin_amdgcn_mfma_f32_32x32x16_bf16(af1, bw, zero16, 0, 0, 0); \
        const int cand = (w * 64 + tb + KOFF) * 32 + col;                             \
        _Pragma("unroll")                                                             \
        for (int r = 0; r < 16; ++r) {                                                \
            if (a0[r] <= U0[r]) {                                                     \
                const int q0 = (r & 3) + 8 * (r >> 2) + 4 * hi;                       \
                const int pos = atomicAdd(&s_cnt[q0], 1);                             \
                if (pos < CAP2) s_surv[q0][pos] = cand;                               \
            }                                                                         \
            if (a1[r] <= U1[r]) {                                                     \
                const int q1 = 32 + (r & 3) + 8 * (r >> 2) + 4 * hi;                  \
                const int pos = atomicAdd(&s_cnt[q1], 1);                             \
                if (pos < CAP2) s_surv[q1][pos] = cand;                               \
            }                                                                         \
        }                                                                             \
    }

    for (int tt = 0; tt < 16; ++tt) {
        const int tb = tt * 4;
        STEP_B(pf0, 0)
        STEP_B(pf1, 1)
        STEP_B(pf2, 2)
        STEP_B(pf3, 3)
    }
#undef STEP_B
    __syncthreads();                                  // B4

    // ---- Epilogue: exact distances + lex rank (verbatim semantics of proven kernel) --
    for (int qi = 0; qi < 16; ++qi) {
        const int q = w * 16 + qi;
        const int n = min(s_cnt[q], CAP2);
        const float4 qp = pb[n0 + q];
        float d1 = 3.4e38f, d2 = 3.4e38f;
        int i1 = -1, i2 = -1;
        if (lane < n) {
            i1 = s_surv[q][lane];
            const float4 v = pb[i1];
            float dot = qp.x * v.x;
            dot = fmaf(qp.y, v.y, dot);
            dot = fmaf(qp.z, v.z, dot);
            d1 = fmaf(dot, -2.0f, qp.w + v.w);        // identical rounding to reference path
        }
        if (64 + lane < n) {
            i2 = s_surv[q][64 + lane];
            const float4 v = pb[i2];
            float dot = qp.x * v.x;
            dot = fmaf(qp.y, v.y, dot);
            dot = fmaf(qp.z, v.z, dot);
            d2 = fmaf(dot, -2.0f, qp.w + v.w);
        }
        s_rd[w][lane] = d1;      s_ri[w][lane] = i1;
        s_rd[w][64 + lane] = d2; s_ri[w][64 + lane] = i2;
        asm volatile("s_waitcnt lgkmcnt(0)" ::: "memory");   // in-wave LDS producer/consumer
        __builtin_amdgcn_wave_barrier();
        int r1 = 0, r2 = 0;
        for (int k = 0; k < n; ++k) {
            const float dk = s_rd[w][k];
            const int   ik = s_ri[w][k];
            r1 += lex_lt(dk, ik, d1, i1) ? 1 : 0;
            r2 += lex_lt(dk, ik, d2, i2) ? 1 : 0;
        }
        if (lane < n && r1 < KNN)      idx_out[(size_t)(qbase + q) * KNN + r1] = i1;
        if (64 + lane < n && r2 < KNN) idx_out[(size_t)(qbase + q) * KNN + r2] = i2;
        __builtin_amdgcn_wave_barrier();              // scratch WAR across queries (in-wave)
    }
}

// ---------------- Kernel 2: MFMA agg — one wave per point, hi/lo bf16 (r11-proven) ----
#define MIDP 132   // s_mid leading-dim pad: 128 -> 132 breaks bank-aligned row stride
__global__ __launch_bounds__(256) void agg_kernel(
    const float* __restrict__ pts,
    const float* __restrict__ feat,
    const float* __restrict__ w_geom,
    const float* __restrict__ g1, const float* __restrict__ b1,
    const float* __restrict__ m1, const float* __restrict__ v1,
    const float* __restrict__ w_sem,
    const float* __restrict__ g2, const float* __restrict__ b2,
    const float* __restrict__ m2, const float* __restrict__ v2,
    const float* __restrict__ w_fuse,
    const float* __restrict__ g3, const float* __restrict__ b3,
    const float* __restrict__ m3, const float* __restrict__ v3,
    const int* __restrict__ knn_idx,
    float* __restrict__ outp) {

    __shared__ alignas(16) unsigned short s_wsemB[8192];    // 16 frags x 64 lanes x 8 bf16
    __shared__ alignas(16) unsigned short s_wfuseB[8192];
    __shared__ float s_wg[6][64];
    __shared__ float s_s1[64], s_b1[64], s_s2[64], s_b2[64], s_s3[64], s_b3[64];
    __shared__ alignas(16) float s_mid[4][16][MIDP];
    __shared__ float s_pm[4][4][64];
    __shared__ alignas(16) float s_ctrf[4][64];
    __shared__ float s_gd[4][16][4];
    __shared__ int   s_nidx[4][16];
    __shared__ float s_ctrp[4][4];

    const int tid = threadIdx.x;
    const int w = tid >> 6, lane = tid & 63;
    const int r = lane & 15, qd = lane >> 4;

    for (int e = tid; e < 1024; e += 256) {          // e = (kc*4+n0)*64 + ln
        const int ln = e & 63;
        const int o = ((e >> 6) & 3) * 16 + (ln & 15);
        const int c = (e >> 8) * 32 + (ln >> 4) * 8;
        unsigned short ts[8], tf[8];
#pragma unroll
        for (int j = 0; j < 8; ++j) {
            ts[j] = f2bf(w_sem [o * 128 + c + j]);
            tf[j] = f2bf(w_fuse[o * 128 + c + j]);
        }
        *(uint4*)&s_wsemB [e * 8] = *(uint4*)ts;
        *(uint4*)&s_wfuseB[e * 8] = *(uint4*)tf;
    }
    for (int e = tid; e < 384; e += 256) {
        const int c = e >> 6, o = e & 63;
        s_wg[c][o] = w_geom[o * 6 + c];
    }
    if (tid < 64) {
        float s;
        s = g1[tid] / sqrtf(v1[tid] + 1e-5f);
        s_s1[tid] = s; s_b1[tid] = b1[tid] - m1[tid] * s;
        s = g2[tid] / sqrtf(v2[tid] + 1e-5f);
        s_s2[tid] = s; s_b2[tid] = b2[tid] - m2[tid] * s;
        s = g3[tid] / sqrtf(v3[tid] + 1e-5f);
        s_s3[tid] = s; s_b3[tid] = b3[tid] - m3[tid] * s;
    }
    __syncthreads();

    const f32x4 zero = {0.f, 0.f, 0.f, 0.f};

    for (int i = 0; i < 4; ++i) {
        const int pv = blockIdx.x * 16 + w * 4 + i;
        const int b = pv >> 13, n = pv & (NPTS - 1);
        const long pbase = (long)b * NPTS + n;

        if (lane < 16) s_nidx[w][lane] = knn_idx[pbase * KNN + lane];
        s_ctrf[w][lane] = feat[pbase * CH + lane];
        if (lane < 3) s_ctrp[w][lane] = pts[pbase * 3 + lane];
        __syncthreads();                                       // B1

        if (lane < 16) {
            const long nb = (long)b * NPTS + s_nidx[w][lane];
            s_gd[w][lane][0] = pts[nb * 3 + 0] - s_ctrp[w][0];
            s_gd[w][lane][1] = pts[nb * 3 + 1] - s_ctrp[w][1];
            s_gd[w][lane][2] = pts[nb * 3 + 2] - s_ctrp[w][2];
        }

        bf16x8 ah[4], al[4];
        {
            float xs[8];
#pragma unroll
            for (int kc = 0; kc < 2; ++kc) {
#pragma unroll
                for (int j = 0; j < 8; ++j) xs[j] = s_ctrf[w][kc * 32 + qd * 8 + j];
                split8(xs, ah[kc], al[kc]);
            }
            const long nb = (long)b * NPTS + s_nidx[w][r];
            const float* fp = feat + nb * CH;
#pragma unroll
            for (int kc = 0; kc < 2; ++kc) {
                const int base = kc * 32 + qd * 8;
                const float4 v0 = *(const float4*)(fp + base);
                const float4 v1 = *(const float4*)(fp + base + 4);
                xs[0] = v0.x - s_ctrf[w][base + 0];
                xs[1] = v0.y - s_ctrf[w][base + 1];
                xs[2] = v0.z - s_ctrf[w][base + 2];
                xs[3] = v0.w - s_ctrf[w][base + 3];
                xs[4] = v1.x - s_ctrf[w][base + 4];
                xs[5] = v1.y - s_ctrf[w][base + 5];
                xs[6] = v1.z - s_ctrf[w][base + 6];
                xs[7] = v1.w - s_ctrf[w][base + 7];
                split8(xs, ah[2 + kc], al[2 + kc]);
            }
        }
        f32x4 acc[4] = {zero, zero, zero, zero};
#pragma unroll
        for (int kc = 0; kc < 4; ++kc) {
#pragma unroll
            for (int n0 = 0; n0 < 4; ++n0) {
                const bf16x8 bw = *(const bf16x8*)&s_wsemB[((kc * 4 + n0) * 64 + lane) * 8];
                acc[n0] = __builtin_amdgcn_mfma_f32_16x16x32_bf16(ah[kc], bw, acc[n0], 0, 0, 0);
                acc[n0] = __builtin_amdgcn_mfma_f32_16x16x32_bf16(al[kc], bw, acc[n0], 0, 0, 0);
            }
        }
#pragma unroll
        for (int n0 = 0; n0 < 4; ++n0) {
            const int nn = n0 * 16 + r;
            const float sv = s_s2[nn], bv = s_b2[nn];
#pragma unroll
            for (int reg = 0; reg < 4; ++reg) {
                s_mid[w][qd * 4 + reg][64 + nn] = fmaxf(fmaf(acc[n0][reg], sv, bv), 0.f);
            }
        }
        __syncthreads();                                       // B2 (s_gd ready)

        {
            const int o = lane;
            float cg = s_ctrp[w][0] * s_wg[0][o];
            cg = fmaf(s_ctrp[w][1], s_wg[1][o], cg);
            cg = fmaf(s_ctrp[w][2], s_wg[2][o], cg);
            const float s1o = s_s1[o], b1o = s_b1[o];
#pragma unroll
            for (int r2 = 0; r2 < 16; ++r2) {
                float g = cg;
                g = fmaf(s_gd[w][r2][0], s_wg[3][o], g);
                g = fmaf(s_gd[w][r2][1], s_wg[4][o], g);
                g = fmaf(s_gd[w][r2][2], s_wg[5][o], g);
                s_mid[w][r2][o] = fmaxf(fmaf(g, s1o, b1o), 0.f);
            }
        }
        __syncthreads();                                       // B3 (mid complete)

        bf16x8 fh[4], fl[4];
        {
            float xs[8];
#pragma unroll
            for (int kc = 0; kc < 4; ++kc) {
                const float* mp = &s_mid[w][r][kc * 32 + qd * 8];
#pragma unroll
                for (int j = 0; j < 8; ++j) xs[j] = mp[j];
                split8(xs, fh[kc], fl[kc]);
            }
        }
        f32x4 acc2[4] = {zero, zero, zero, zero};
#pragma unroll
        for (int kc = 0; kc < 4; ++kc) {
#pragma unroll
            for (int n0 = 0; n0 < 4; ++n0) {
                const bf16x8 bw = *(const bf16x8*)&s_wfuseB[((kc * 4 + n0) * 64 + lane) * 8];
                acc2[n0] = __builtin_amdgcn_mfma_f32_16x16x32_bf16(fh[kc], bw, acc2[n0], 0, 0, 0);
                acc2[n0] = __builtin_amdgcn_mfma_f32_16x16x32_bf16(fl[kc], bw, acc2[n0], 0, 0, 0);
            }
        }
#pragma unroll
        for (int n0 = 0; n0 < 4; ++n0) {
            const int nn = n0 * 16 + r;
            const float sv = s_s3[nn], bv = s_b3[nn];
            float mx = 0.f;   // relu outputs >= 0
#pragma unroll
            for (int reg = 0; reg < 4; ++reg)
                mx = fmaxf(mx, fmaxf(fmaf(acc2[n0][reg], sv, bv), 0.f));
            s_pm[w][qd][nn] = mx;
        }
        __syncthreads();                                       // B4
        {
            const int o = lane;
            const float rv = fmaxf(fmaxf(s_pm[w][0][o], s_pm[w][1][o]),
                                   fmaxf(s_pm[w][2][o], s_pm[w][3][o]));
            outp[pbase * CH + o] = rv;
        }
        __syncthreads();                                       // B5 (WAR across iters)
    }
}

extern "C" void kernel_launch(void* const* d_in, const int* in_sizes, int n_in,
                              void* d_out, int out_size, void* d_ws, size_t ws_size,
                              hipStream_t stream) {
    (void)in_sizes; (void)n_in; (void)out_size; (void)ws_size;
    const float* pts    = (const float*)d_in[0];
    const float* feat   = (const float*)d_in[1];
    const float* w_geom = (const float*)d_in[2];
    const float* g1     = (const float*)d_in[3];
    const float* b1     = (const float*)d_in[4];
    const float* m1     = (const float*)d_in[5];
    const float* v1     = (const float*)d_in[6];
    const float* w_sem  = (const float*)d_in[7];
    const float* g2     = (const float*)d_in[8];
    const float* b2     = (const float*)d_in[9];
    const float* m2     = (const float*)d_in[10];
    const float* v2     = (const float*)d_in[11];
    const float* w_fuse = (const float*)d_in[12];
    const float* g3     = (const float*)d_in[13];
    const float* b3     = (const float*)d_in[14];
    const float* m3     = (const float*)d_in[15];
    const float* v3     = (const float*)d_in[16];

    int*    idx_final = (int*)d_ws;                             // 2 MB @ 0
    uint4*  bfrag     = (uint4*)((char*)d_ws + (2ull << 20));   // 1 MB @ 2MB
    float4* pts4      = (float4*)((char*)d_ws + (4ull << 20));  // 512 KB @ 4MB

    pack_kernel<<<dim3(NB * NPTS / 256), dim3(256), 0, stream>>>(pts, pts4, bfrag);
    knn_mfma_kernel<<<dim3(NB * NPTS / 64), dim3(256), 0, stream>>>(pts4, bfrag, idx_final);

    agg_kernel<<<dim3(2048), dim3(256), 0, stream>>>(
        pts, feat, w_geom, g1, b1, m1, v1, w_sem, g2, b2, m2, v2,
        w_fuse, g3, b3, m3, v3, idx_final, (float*)d_out);
}

// Round 3
// 304.656 us; speedup vs baseline: 1.1098x; 1.0408x over previous
//
#include <hip/hip_runtime.h>

#define NPTS 8192
#define NB 4
#define CH 64
#define KNN 16
#define CAP2 128          // survivors per query (expected ~20-40; passed 2 rounds at 128)
#define SLACK 4e-3f       // > 2*eps of bf16 hi/lo MFMA distance approx (eps ~ 5e-4)
#define MNVP 129          // s_minv pad: 129 % 32 = 1 -> conflict-free column reads

using bf16x8 = __attribute__((ext_vector_type(8))) __bf16;
using us8    = __attribute__((ext_vector_type(8))) unsigned short;
using f32x4  = __attribute__((ext_vector_type(4))) float;
using f32x16 = __attribute__((ext_vector_type(16))) float;

__device__ __forceinline__ float bf2f(unsigned short u) {
    return __uint_as_float(((unsigned)u) << 16);
}
__device__ __forceinline__ unsigned short f2bf(float f) {
    unsigned u = __float_as_uint(f);
    u += 0x7fffu + ((u >> 16) & 1u);
    return (unsigned short)(u >> 16);
}

// split 8 f32 into hi/lo bf16 fragments: x = hi + lo to ~16 extra mantissa bits
__device__ __forceinline__ void split8(const float* x, bf16x8& hi, bf16x8& lo) {
    us8 h, l;
#pragma unroll
    for (int j = 0; j < 8; ++j) {
        const unsigned short hb = f2bf(x[j]);
        h[j] = hb;
        l[j] = f2bf(x[j] - bf2f(hb));
    }
    hi = __builtin_bit_cast(bf16x8, h);
    lo = __builtin_bit_cast(bf16x8, l);
}

// lexicographic (d,i) compare: true if (dB,iB) < (dA,iA)
__device__ __forceinline__ bool lex_lt(float dB, int iB, float dA, int iA) {
    return (dB < dA) || ((dB == dA) && (iB < iA));
}

// ---------------- Kernel 0: pack {x,y,z,sq} + 32x32x16 MFMA B-fragments --------------
// K=16 plan (14 used slots), B layout: col=lane&31 (candidate), k=(lane>>5)*8+j.
//   kh=0 (k0..7):  (-2c)h.xyz, (-2c)l.xyz, (-2c)h.xy
//   kh=1 (k8..15): (-2c)h.z, (-2c)l.xyz, sq_hi, sq_lo, 0, 0
// Paired with A (query):
//   kh=0: qh.xyz, qh.xyz, ql.xy    kh=1: ql.z, ql.xyz, 1, 1, 0, 0
//  => D = (qh+ql)·((-2c)h+(-2c)l) + sq_c  =  |c|^2 - 2 q·c   (err ~5e-4 abs)
__global__ __launch_bounds__(256) void pack_kernel(const float* __restrict__ pts,
                                                   float4* __restrict__ pts4,
                                                   uint4* __restrict__ bfrag) {
    const int i = blockIdx.x * 256 + threadIdx.x;   // 0..32767
    const float x = pts[i * 3 + 0];
    const float y = pts[i * 3 + 1];
    const float z = pts[i * 3 + 2];
    const float sq = (x * x + y * y) + z * z;       // reference-path formula
    pts4[i] = make_float4(x, y, z, sq);

    const float sx = -2.f * x, sy = -2.f * y, sz = -2.f * z;
    const unsigned short shx = f2bf(sx), shy = f2bf(sy), shz = f2bf(sz);
    const unsigned short slx = f2bf(sx - bf2f(shx));
    const unsigned short sly = f2bf(sy - bf2f(shy));
    const unsigned short slz = f2bf(sz - bf2f(shz));
    const unsigned short sqh = f2bf(sq), sql = f2bf(sq - bf2f(sqh));

    const int b = i >> 13, n = i & (NPTS - 1);
    const int tile = n >> 5, col = n & 31;
    uint4* base = bfrag + ((size_t)(b * 256 + tile)) * 64;

    unsigned short g0[8], g1[8];
    g0[0] = shx; g0[1] = shy; g0[2] = shz; g0[3] = slx;
    g0[4] = sly; g0[5] = slz; g0[6] = shx; g0[7] = shy;   // k0..7
    g1[0] = shz; g1[1] = slx; g1[2] = sly; g1[3] = slz;
    g1[4] = sqh; g1[5] = sql; g1[6] = 0;   g1[7] = 0;     // k8..15
    base[col]      = *(const uint4*)g0;
    base[32 + col] = *(const uint4*)g1;
}

// A-fragment for one query point, k-half kh = lane>>5 (proven k-plan)
__device__ __forceinline__ bf16x8 make_afrag(const float4 qp, const int kh) {
    const unsigned short hx = f2bf(qp.x), hy = f2bf(qp.y), hz = f2bf(qp.z);
    const unsigned short lx = f2bf(qp.x - bf2f(hx));
    const unsigned short ly = f2bf(qp.y - bf2f(hy));
    const unsigned short lz = f2bf(qp.z - bf2f(hz));
    us8 u;
#pragma unroll
    for (int j = 0; j < 8; ++j) u[j] = 0;
    if (kh == 0) {
        u[0] = hx; u[1] = hy; u[2] = hz; u[3] = hx;
        u[4] = hy; u[5] = hz; u[6] = lx; u[7] = ly;       // k0..7
    } else {
        u[0] = lz; u[1] = lx; u[2] = ly; u[3] = lz;
        u[4] = 0x3f80u; u[5] = 0x3f80u;                   // 1.0 * sq_hi/lo, k8..15
    }
    return __builtin_bit_cast(bf16x8, u);
}

// ---------------- Kernel 1: MFMA KNN (32x32x16, candidate-quartered waves) -----------
// Block = 4 waves = 64 queries of one batch. Wave w covers candidate tiles
// [w*64, w*64+64). Pass A: per-wave stream minima (32 cand-classes x 4 waves = 128
// streams/query), combined to 64; U = rank-15 of 64 stream minima. Pass B: admit
// e <= U+SLACK via LDS atomics. Epilogue: exact f32 distances + lex-(d,idx) rank.
// LDS: s_minv (dead after B3) and s_surv (live after B3) share one union region ->
// 37.6 KB total -> 4 blocks/CU (vs 70.6 KB / 2 blocks in prior round).
__global__ __launch_bounds__(256, 4) void knn_mfma_kernel(const float4* __restrict__ pts4,
                                                          const uint4* __restrict__ bfrag,
                                                          int* __restrict__ idx_out) {
    __shared__ alignas(16) char s_union[64 * MNVP * 4];   // 33,024 B
    float (*s_minv)[MNVP] = (float(*)[MNVP])s_union;      // [64][129], dead after B3
    int   (*s_surv)[CAP2] = (int(*)[CAP2])s_union;        // [64][128], written after B3
    __shared__ float s_U[64];
    __shared__ int   s_cnt[64];
    __shared__ float s_rd[4][CAP2];
    __shared__ int   s_ri[4][CAP2];

    const int tid  = threadIdx.x;
    const int w    = tid >> 6, lane = tid & 63;
    const int col  = lane & 31, hi = lane >> 5;
    const int qbase = blockIdx.x * 64;               // global query id (= b*8192 + n0)
    const int b = qbase >> 13, n0 = qbase & (NPTS - 1);
    const float4* pb = pts4 + (size_t)b * NPTS;

    // A-fragments: rows = queries. Set0 = n0..n0+31, set1 = n0+32..n0+63.
    const bf16x8 af0 = make_afrag(pb[n0 + col], hi);
    const bf16x8 af1 = make_afrag(pb[n0 + 32 + col], hi);

    // per-lane B pointer for this wave's 64 tiles (1 KB/tile, 16 B/lane)
    const uint4* bpl = bfrag + ((size_t)(b * 256 + w * 64)) * 64 + lane;
    const f32x16 zero16 = {0.f, 0.f, 0.f, 0.f, 0.f, 0.f, 0.f, 0.f,
                           0.f, 0.f, 0.f, 0.f, 0.f, 0.f, 0.f, 0.f};

    // ---- Pass A: stream minima of e = |c|^2 - 2 q.c, 4-deep prefetch ring ----
    // Refills are UNCONDITIONAL: last iteration over-reads <=4 KB past this wave's
    // region. Worst case (batch 3, wave 3) lands in the unused d_ws gap at 3MB..3MB+4KB
    // (bfrag = 2MB..3MB, pts4 = 4MB..4.5MB) -- address-safe, values never consumed.
    float m0[16], m1[16];
#pragma unroll
    for (int r = 0; r < 16; ++r) { m0[r] = 3.4e38f; m1[r] = 3.4e38f; }

    uint4 pf0 = bpl[0 * 64], pf1 = bpl[1 * 64], pf2 = bpl[2 * 64], pf3 = bpl[3 * 64];

#define STEP_A(PF, KOFF)                                                              \
    {                                                                                 \
        const bf16x8 bw = __builtin_bit_cast(bf16x8, PF);                             \
        PF = bpl[(tb + 4 + KOFF) * 64];                                               \
        const f32x16 a0 = __builtin_amdgcn_mfma_f32_32x32x16_bf16(af0, bw, zero16, 0, 0, 0); \
        const f32x16 a1 = __builtin_amdgcn_mfma_f32_32x32x16_bf16(af1, bw, zero16, 0, 0, 0); \
        _Pragma("unroll")                                                             \
        for (int r = 0; r < 16; ++r) {                                                \
            m0[r] = fminf(m0[r], a0[r]);                                              \
            m1[r] = fminf(m1[r], a1[r]);                                              \
        }                                                                             \
    }

    for (int tt = 0; tt < 16; ++tt) {
        const int tb = tt * 4;
        STEP_A(pf0, 0)
        STEP_A(pf1, 1)
        STEP_A(pf2, 2)
        STEP_A(pf3, 3)
    }
#undef STEP_A

    // C/D layout (verified): col=lane&31 (cand-class), row=(r&3)+8*(r>>2)+4*hi (query).
    // stream id = w*32 + col.
#pragma unroll
    for (int r = 0; r < 16; ++r) {
        const int q0 = (r & 3) + 8 * (r >> 2) + 4 * hi;
        s_minv[q0][w * 32 + col]      = m0[r];
        s_minv[32 + q0][w * 32 + col] = m1[r];
    }
    if (tid < 64) s_cnt[tid] = 0;
    __syncthreads();                                  // B1 (all 128 streams written)

    // ---- combine 128 -> 64 streams (pairwise min over disjoint candidate sets) ----
    for (int e = tid; e < 64 * 64; e += 256) {
        const int q = e >> 6, j = e & 63;
        s_minv[q][j] = fminf(s_minv[q][j], s_minv[q][64 + j]);
    }
    __syncthreads();                                  // B2

    // ---- U select: rank-15 (16th smallest) of 64 stream minima per query ----
    for (int qi = 0; qi < 16; ++qi) {
        const int q = w * 16 + qi;
        const float v = s_minv[q][lane];
        int rk = 0;
        for (int j = 0; j < 64; ++j) {
            const float vv = s_minv[q][j];
            rk += ((vv < v) || (vv == v && j < lane)) ? 1 : 0;
        }
        if (rk == 15) s_U[q] = v;                     // exactly one (value,stream) wins
    }
    __syncthreads();                                  // B3 (last s_minv read; s_surv may now be written)

    // ---- Pass B: gated admission ----
    float U0[16], U1[16];
#pragma unroll
    for (int r = 0; r < 16; ++r) {
        const int q0 = (r & 3) + 8 * (r >> 2) + 4 * hi;
        U0[r] = s_U[q0] + SLACK;
        U1[r] = s_U[32 + q0] + SLACK;
    }

    pf0 = bpl[0 * 64]; pf1 = bpl[1 * 64]; pf2 = bpl[2 * 64]; pf3 = bpl[3 * 64];

#define STEP_B(PF, KOFF)                                                              \
    {                                                                                 \
        const bf16x8 bw = __builtin_bit_cast(bf16x8, PF);                             \
        PF = bpl[(tb + 4 + KOFF) * 64];                                               \
        const f32x16 a0 = __builtin_amdgcn_mfma_f32_32x32x16_bf16(af0, bw, zero16, 0, 0, 0); \
        const f32x16 a1 = __builtin_amdgcn_mfma_f32_32x32x16_bf16(af1, bw, zero16, 0, 0, 0); \
        const int cand = (w * 64 + tb + KOFF) * 32 + col;                             \
        _Pragma("unroll")                                                             \
        for (int r = 0; r < 16; ++r) {                                                \
            if (a0[r] <= U0[r]) {                                                     \
                const int q0 = (r & 3) + 8 * (r >> 2) + 4 * hi;                       \
                const int pos = atomicAdd(&s_cnt[q0], 1);                             \
                if (pos < CAP2) s_surv[q0][pos] = cand;                               \
            }                                                                         \
            if (a1[r] <= U1[r]) {                                                     \
                const int q1 = 32 + (r & 3) + 8 * (r >> 2) + 4 * hi;                  \
                const int pos = atomicAdd(&s_cnt[q1], 1);                             \
                if (pos < CAP2) s_surv[q1][pos] = cand;                               \
            }                                                                         \
        }                                                                             \
    }

    for (int tt = 0; tt < 16; ++tt) {
        const int tb = tt * 4;
        STEP_B(pf0, 0)
        STEP_B(pf1, 1)
        STEP_B(pf2, 2)
        STEP_B(pf3, 3)
    }
#undef STEP_B
    __syncthreads();                                  // B4

    // ---- Epilogue: exact distances + lex rank (verbatim semantics of proven kernel) --
    for (int qi = 0; qi < 16; ++qi) {
        const int q = w * 16 + qi;
        const int n = min(s_cnt[q], CAP2);
        const float4 qp = pb[n0 + q];
        float d1 = 3.4e38f, d2 = 3.4e38f;
        int i1 = -1, i2 = -1;
        if (lane < n) {
            i1 = s_surv[q][lane];
            const float4 v = pb[i1];
            float dot = qp.x * v.x;
            dot = fmaf(qp.y, v.y, dot);
            dot = fmaf(qp.z, v.z, dot);
            d1 = fmaf(dot, -2.0f, qp.w + v.w);        // identical rounding to reference path
        }
        if (64 + lane < n) {
            i2 = s_surv[q][64 + lane];
            const float4 v = pb[i2];
            float dot = qp.x * v.x;
            dot = fmaf(qp.y, v.y, dot);
            dot = fmaf(qp.z, v.z, dot);
            d2 = fmaf(dot, -2.0f, qp.w + v.w);
        }
        s_rd[w][lane] = d1;      s_ri[w][lane] = i1;
        s_rd[w][64 + lane] = d2; s_ri[w][64 + lane] = i2;
        asm volatile("s_waitcnt lgkmcnt(0)" ::: "memory");   // in-wave LDS producer/consumer
        __builtin_amdgcn_wave_barrier();
        int r1 = 0, r2 = 0;
        for (int k = 0; k < n; ++k) {
            const float dk = s_rd[w][k];
            const int   ik = s_ri[w][k];
            r1 += lex_lt(dk, ik, d1, i1) ? 1 : 0;
            r2 += lex_lt(dk, ik, d2, i2) ? 1 : 0;
        }
        if (lane < n && r1 < KNN)      idx_out[(size_t)(qbase + q) * KNN + r1] = i1;
        if (64 + lane < n && r2 < KNN) idx_out[(size_t)(qbase + q) * KNN + r2] = i2;
        __builtin_amdgcn_wave_barrier();              // scratch WAR across queries (in-wave)
    }
}

// ---------------- Kernel 2: MFMA agg — one wave per point, hi/lo bf16 (r11-proven) ----
#define MIDP 132   // s_mid leading-dim pad: 128 -> 132 breaks bank-aligned row stride
__global__ __launch_bounds__(256) void agg_kernel(
    const float* __restrict__ pts,
    const float* __restrict__ feat,
    const float* __restrict__ w_geom,
    const float* __restrict__ g1, const float* __restrict__ b1,
    const float* __restrict__ m1, const float* __restrict__ v1,
    const float* __restrict__ w_sem,
    const float* __restrict__ g2, const float* __restrict__ b2,
    const float* __restrict__ m2, const float* __restrict__ v2,
    const float* __restrict__ w_fuse,
    const float* __restrict__ g3, const float* __restrict__ b3,
    const float* __restrict__ m3, const float* __restrict__ v3,
    const int* __restrict__ knn_idx,
    float* __restrict__ outp) {

    __shared__ alignas(16) unsigned short s_wsemB[8192];    // 16 frags x 64 lanes x 8 bf16
    __shared__ alignas(16) unsigned short s_wfuseB[8192];
    __shared__ float s_wg[6][64];
    __shared__ float s_s1[64], s_b1[64], s_s2[64], s_b2[64], s_s3[64], s_b3[64];
    __shared__ alignas(16) float s_mid[4][16][MIDP];
    __shared__ float s_pm[4][4][64];
    __shared__ alignas(16) float s_ctrf[4][64];
    __shared__ float s_gd[4][16][4];
    __shared__ int   s_nidx[4][16];
    __shared__ float s_ctrp[4][4];

    const int tid = threadIdx.x;
    const int w = tid >> 6, lane = tid & 63;
    const int r = lane & 15, qd = lane >> 4;

    for (int e = tid; e < 1024; e += 256) {          // e = (kc*4+n0)*64 + ln
        const int ln = e & 63;
        const int o = ((e >> 6) & 3) * 16 + (ln & 15);
        const int c = (e >> 8) * 32 + (ln >> 4) * 8;
        unsigned short ts[8], tf[8];
#pragma unroll
        for (int j = 0; j < 8; ++j) {
            ts[j] = f2bf(w_sem [o * 128 + c + j]);
            tf[j] = f2bf(w_fuse[o * 128 + c + j]);
        }
        *(uint4*)&s_wsemB [e * 8] = *(uint4*)ts;
        *(uint4*)&s_wfuseB[e * 8] = *(uint4*)tf;
    }
    for (int e = tid; e < 384; e += 256) {
        const int c = e >> 6, o = e & 63;
        s_wg[c][o] = w_geom[o * 6 + c];
    }
    if (tid < 64) {
        float s;
        s = g1[tid] / sqrtf(v1[tid] + 1e-5f);
        s_s1[tid] = s; s_b1[tid] = b1[tid] - m1[tid] * s;
        s = g2[tid] / sqrtf(v2[tid] + 1e-5f);
        s_s2[tid] = s; s_b2[tid] = b2[tid] - m2[tid] * s;
        s = g3[tid] / sqrtf(v3[tid] + 1e-5f);
        s_s3[tid] = s; s_b3[tid] = b3[tid] - m3[tid] * s;
    }
    __syncthreads();

    const f32x4 zero = {0.f, 0.f, 0.f, 0.f};

    for (int i = 0; i < 4; ++i) {
        const int pv = blockIdx.x * 16 + w * 4 + i;
        const int b = pv >> 13, n = pv & (NPTS - 1);
        const long pbase = (long)b * NPTS + n;

        if (lane < 16) s_nidx[w][lane] = knn_idx[pbase * KNN + lane];
        s_ctrf[w][lane] = feat[pbase * CH + lane];
        if (lane < 3) s_ctrp[w][lane] = pts[pbase * 3 + lane];
        __syncthreads();                                       // B1

        if (lane < 16) {
            const long nb = (long)b * NPTS + s_nidx[w][lane];
            s_gd[w][lane][0] = pts[nb * 3 + 0] - s_ctrp[w][0];
            s_gd[w][lane][1] = pts[nb * 3 + 1] - s_ctrp[w][1];
            s_gd[w][lane][2] = pts[nb * 3 + 2] - s_ctrp[w][2];
        }

        bf16x8 ah[4], al[4];
        {
            float xs[8];
#pragma unroll
            for (int kc = 0; kc < 2; ++kc) {
#pragma unroll
                for (int j = 0; j < 8; ++j) xs[j] = s_ctrf[w][kc * 32 + qd * 8 + j];
                split8(xs, ah[kc], al[kc]);
            }
            const long nb = (long)b * NPTS + s_nidx[w][r];
            const float* fp = feat + nb * CH;
#pragma unroll
            for (int kc = 0; kc < 2; ++kc) {
                const int base = kc * 32 + qd * 8;
                const float4 v0 = *(const float4*)(fp + base);
                const float4 v1 = *(const float4*)(fp + base + 4);
                xs[0] = v0.x - s_ctrf[w][base + 0];
                xs[1] = v0.y - s_ctrf[w][base + 1];
                xs[2] = v0.z - s_ctrf[w][base + 2];
                xs[3] = v0.w - s_ctrf[w][base + 3];
                xs[4] = v1.x - s_ctrf[w][base + 4];
                xs[5] = v1.y - s_ctrf[w][base + 5];
                xs[6] = v1.z - s_ctrf[w][base + 6];
                xs[7] = v1.w - s_ctrf[w][base + 7];
                split8(xs, ah[2 + kc], al[2 + kc]);
            }
        }
        f32x4 acc[4] = {zero, zero, zero, zero};
#pragma unroll
        for (int kc = 0; kc < 4; ++kc) {
#pragma unroll
            for (int n0 = 0; n0 < 4; ++n0) {
                const bf16x8 bw = *(const bf16x8*)&s_wsemB[((kc * 4 + n0) * 64 + lane) * 8];
                acc[n0] = __builtin_amdgcn_mfma_f32_16x16x32_bf16(ah[kc], bw, acc[n0], 0, 0, 0);
                acc[n0] = __builtin_amdgcn_mfma_f32_16x16x32_bf16(al[kc], bw, acc[n0], 0, 0, 0);
            }
        }
#pragma unroll
        for (int n0 = 0; n0 < 4; ++n0) {
            const int nn = n0 * 16 + r;
            const float sv = s_s2[nn], bv = s_b2[nn];
#pragma unroll
            for (int reg = 0; reg < 4; ++reg) {
                s_mid[w][qd * 4 + reg][64 + nn] = fmaxf(fmaf(acc[n0][reg], sv, bv), 0.f);
            }
        }
        __syncthreads();                                       // B2 (s_gd ready)

        {
            const int o = lane;
            float cg = s_ctrp[w][0] * s_wg[0][o];
            cg = fmaf(s_ctrp[w][1], s_wg[1][o], cg);
            cg = fmaf(s_ctrp[w][2], s_wg[2][o], cg);
            const float s1o = s_s1[o], b1o = s_b1[o];
#pragma unroll
            for (int r2 = 0; r2 < 16; ++r2) {
                float g = cg;
                g = fmaf(s_gd[w][r2][0], s_wg[3][o], g);
                g = fmaf(s_gd[w][r2][1], s_wg[4][o], g);
                g = fmaf(s_gd[w][r2][2], s_wg[5][o], g);
                s_mid[w][r2][o] = fmaxf(fmaf(g, s1o, b1o), 0.f);
            }
        }
        __syncthreads();                                       // B3 (mid complete)

        bf16x8 fh[4], fl[4];
        {
            float xs[8];
#pragma unroll
            for (int kc = 0; kc < 4; ++kc) {
                const float* mp = &s_mid[w][r][kc * 32 + qd * 8];
#pragma unroll
                for (int j = 0; j < 8; ++j) xs[j] = mp[j];
                split8(xs, fh[kc], fl[kc]);
            }
        }
        f32x4 acc2[4] = {zero, zero, zero, zero};
#pragma unroll
        for (int kc = 0; kc < 4; ++kc) {
#pragma unroll
            for (int n0 = 0; n0 < 4; ++n0) {
                const bf16x8 bw = *(const bf16x8*)&s_wfuseB[((kc * 4 + n0) * 64 + lane) * 8];
                acc2[n0] = __builtin_amdgcn_mfma_f32_16x16x32_bf16(fh[kc], bw, acc2[n0], 0, 0, 0);
                acc2[n0] = __builtin_amdgcn_mfma_f32_16x16x32_bf16(fl[kc], bw, acc2[n0], 0, 0, 0);
            }
        }
#pragma unroll
        for (int n0 = 0; n0 < 4; ++n0) {
            const int nn = n0 * 16 + r;
            const float sv = s_s3[nn], bv = s_b3[nn];
            float mx = 0.f;   // relu outputs >= 0
#pragma unroll
            for (int reg = 0; reg < 4; ++reg)
                mx = fmaxf(mx, fmaxf(fmaf(acc2[n0][reg], sv, bv), 0.f));
            s_pm[w][qd][nn] = mx;
        }
        __syncthreads();                                       // B4
        {
            const int o = lane;
            const float rv = fmaxf(fmaxf(s_pm[w][0][o], s_pm[w][1][o]),
                                   fmaxf(s_pm[w][2][o], s_pm[w][3][o]));
            outp[pbase * CH + o] = rv;
        }
        __syncthreads();                                       // B5 (WAR across iters)
    }
}

extern "C" void kernel_launch(void* const* d_in, const int* in_sizes, int n_in,
                              void* d_out, int out_size, void* d_ws, size_t ws_size,
                              hipStream_t stream) {
    (void)in_sizes; (void)n_in; (void)out_size; (void)ws_size;
    const float* pts    = (const float*)d_in[0];
    const float* feat   = (const float*)d_in[1];
    const float* w_geom = (const float*)d_in[2];
    const float* g1     = (const float*)d_in[3];
    const float* b1     = (const float*)d_in[4];
    const float* m1     = (const float*)d_in[5];
    const float* v1     = (const float*)d_in[6];
    const float* w_sem  = (const float*)d_in[7];
    const float* g2     = (const float*)d_in[8];
    const float* b2     = (const float*)d_in[9];
    const float* m2     = (const float*)d_in[10];
    const float* v2     = (const float*)d_in[11];
    const float* w_fuse = (const float*)d_in[12];
    const float* g3     = (const float*)d_in[13];
    const float* b3     = (const float*)d_in[14];
    const float* m3     = (const float*)d_in[15];
    const float* v3     = (const float*)d_in[16];

    int*    idx_final = (int*)d_ws;                             // 2 MB @ 0
    uint4*  bfrag     = (uint4*)((char*)d_ws + (2ull << 20));   // 1 MB @ 2MB (gap to 4MB absorbs prefetch over-read)
    float4* pts4      = (float4*)((char*)d_ws + (4ull << 20));  // 512 KB @ 4MB

    pack_kernel<<<dim3(NB * NPTS / 256), dim3(256), 0, stream>>>(pts, pts4, bfrag);
    knn_mfma_kernel<<<dim3(NB * NPTS / 64), dim3(256), 0, stream>>>(pts4, bfrag, idx_final);

    agg_kernel<<<dim3(2048), dim3(256), 0, stream>>>(
        pts, feat, w_geom, g1, b1, m1, v1, w_sem, g2, b2, m2, v2,
        w_fuse, g3, b3, m3, v3, idx_final, (float*)d_out);
}

// Round 5
// 264.524 us; speedup vs baseline: 1.2782x; 1.1517x over previous
//
#include <hip/hip_runtime.h>

#define NPTS 8192
#define NB 4
#define CH 64
#define KNN 16
#define CAP2 128          // survivors per query (expected ~20-40; passed 3 rounds at 128)
#define SLACK 4e-3f       // > 2*eps of bf16 hi/lo MFMA distance approx (eps ~ 5e-4)
#define MNVP 129          // s_minv pad: 129 % 32 = 1 -> conflict-free column reads

using bf16x8 = __attribute__((ext_vector_type(8))) __bf16;
using us8    = __attribute__((ext_vector_type(8))) unsigned short;
using f32x4  = __attribute__((ext_vector_type(4))) float;
using f32x16 = __attribute__((ext_vector_type(16))) float;

__device__ __forceinline__ float bf2f(unsigned short u) {
    return __uint_as_float(((unsigned)u) << 16);
}
__device__ __forceinline__ unsigned short f2bf(float f) {
    unsigned u = __float_as_uint(f);
    u += 0x7fffu + ((u >> 16) & 1u);
    return (unsigned short)(u >> 16);
}

// split 8 f32 into hi/lo bf16 fragments: x = hi + lo to ~16 extra mantissa bits
__device__ __forceinline__ void split8(const float* x, bf16x8& hi, bf16x8& lo) {
    us8 h, l;
#pragma unroll
    for (int j = 0; j < 8; ++j) {
        const unsigned short hb = f2bf(x[j]);
        h[j] = hb;
        l[j] = f2bf(x[j] - bf2f(hb));
    }
    hi = __builtin_bit_cast(bf16x8, h);
    lo = __builtin_bit_cast(bf16x8, l);
}

// lexicographic (d,i) compare: true if (dB,iB) < (dA,iA)
__device__ __forceinline__ bool lex_lt(float dB, int iB, float dA, int iA) {
    return (dB < dA) || ((dB == dA) && (iB < iA));
}

// ---------------- Kernel 0: pack {x,y,z,sq} + 32x32x16 MFMA B-fragments --------------
// K=16 plan (14 used slots), B layout: col=lane&31 (candidate), k=(lane>>5)*8+j.
//   kh=0 (k0..7):  (-2c)h.xyz, (-2c)l.xyz, (-2c)h.xy
//   kh=1 (k8..15): (-2c)h.z, (-2c)l.xyz, sq_hi, sq_lo, 0, 0
// Paired with A (query):
//   kh=0: qh.xyz, qh.xyz, ql.xy    kh=1: ql.z, ql.xyz, 1, 1, 0, 0
//  => D = (qh+ql)·((-2c)h+(-2c)l) + sq_c  =  |c|^2 - 2 q·c   (err ~5e-4 abs)
__global__ __launch_bounds__(256) void pack_kernel(const float* __restrict__ pts,
                                                   float4* __restrict__ pts4,
                                                   uint4* __restrict__ bfrag) {
    const int i = blockIdx.x * 256 + threadIdx.x;   // 0..32767
    const float x = pts[i * 3 + 0];
    const float y = pts[i * 3 + 1];
    const float z = pts[i * 3 + 2];
    const float sq = (x * x + y * y) + z * z;       // reference-path formula
    pts4[i] = make_float4(x, y, z, sq);

    const float sx = -2.f * x, sy = -2.f * y, sz = -2.f * z;
    const unsigned short shx = f2bf(sx), shy = f2bf(sy), shz = f2bf(sz);
    const unsigned short slx = f2bf(sx - bf2f(shx));
    const unsigned short sly = f2bf(sy - bf2f(shy));
    const unsigned short slz = f2bf(sz - bf2f(shz));
    const unsigned short sqh = f2bf(sq), sql = f2bf(sq - bf2f(sqh));

    const int b = i >> 13, n = i & (NPTS - 1);
    const int tile = n >> 5, col = n & 31;
    uint4* base = bfrag + ((size_t)(b * 256 + tile)) * 64;

    unsigned short g0[8], g1[8];
    g0[0] = shx; g0[1] = shy; g0[2] = shz; g0[3] = slx;
    g0[4] = sly; g0[5] = slz; g0[6] = shx; g0[7] = shy;   // k0..7
    g1[0] = shz; g1[1] = slx; g1[2] = sly; g1[3] = slz;
    g1[4] = sqh; g1[5] = sql; g1[6] = 0;   g1[7] = 0;     // k8..15
    base[col]      = *(const uint4*)g0;
    base[32 + col] = *(const uint4*)g1;
}

// A-fragment for one query point, k-half kh = lane>>5 (proven k-plan)
__device__ __forceinline__ bf16x8 make_afrag(const float4 qp, const int kh) {
    const unsigned short hx = f2bf(qp.x), hy = f2bf(qp.y), hz = f2bf(qp.z);
    const unsigned short lx = f2bf(qp.x - bf2f(hx));
    const unsigned short ly = f2bf(qp.y - bf2f(hy));
    const unsigned short lz = f2bf(qp.z - bf2f(hz));
    us8 u;
#pragma unroll
    for (int j = 0; j < 8; ++j) u[j] = 0;
    if (kh == 0) {
        u[0] = hx; u[1] = hy; u[2] = hz; u[3] = hx;
        u[4] = hy; u[5] = hz; u[6] = lx; u[7] = ly;       // k0..7
    } else {
        u[0] = lz; u[1] = lx; u[2] = ly; u[3] = lz;
        u[4] = 0x3f80u; u[5] = 0x3f80u;                   // 1.0 * sq_hi/lo, k8..15
    }
    return __builtin_bit_cast(bf16x8, u);
}

// ---------------- Kernel 1: MFMA KNN (32x32x16, candidate-quartered waves) -----------
// Block = 4 waves = 32 queries of one batch (ONE 32-query MFMA row-set). Wave w covers
// candidate tiles [w*64, w*64+64). Grid = 1024 blocks -> 4 blocks/CU, 16 waves/CU
// (round-3 was grid-limited at 2 blocks/CU / 22% occupancy).
// Pass A: per-wave stream minima (32 cand-classes x 4 waves = 128 streams/query),
// combined to 64; U = rank-15 of 64 stream minima. Pass B: admit e <= U+SLACK via LDS
// atomics. Epilogue: exact f32 distances + lex-(d,idx) rank (byte-identical semantics).
// LDS: s_minv (dead after B3) unions with s_surv (written after B3) -> ~21 KB total.
// Prefetch refill indices are clamped with min(idx,255): wave-uniform -> one SALU
// s_min per refill, NO branch (not the round-2 conditional-refill regression). All
// loads provably inside bfrag's 1 MB.
__global__ __launch_bounds__(256, 4) void knn_mfma_kernel(const float4* __restrict__ pts4,
                                                          const uint4* __restrict__ bfrag,
                                                          int* __restrict__ idx_out) {
    __shared__ alignas(16) char s_union[32 * MNVP * 4];   // 16,512 B
    float (*s_minv)[MNVP] = (float(*)[MNVP])s_union;      // [32][129], dead after B3
    int   (*s_surv)[CAP2] = (int(*)[CAP2])s_union;        // [32][128], written after B3
    __shared__ float s_U[32];
    __shared__ int   s_cnt[32];
    __shared__ float s_rd[4][CAP2];
    __shared__ int   s_ri[4][CAP2];

    const int tid  = threadIdx.x;
    const int w    = tid >> 6, lane = tid & 63;
    const int col  = lane & 31, hi = lane >> 5;
    const int qbase = blockIdx.x * 32;               // global query id (= b*8192 + n0)
    const int b = qbase >> 13, n0 = qbase & (NPTS - 1);
    const float4* pb = pts4 + (size_t)b * NPTS;

    // A-fragment: rows = queries n0..n0+31
    const bf16x8 af = make_afrag(pb[n0 + col], hi);

    // per-lane B pointer for this wave's 64 tiles (1 KB/tile, 16 B/lane).
    // wtile = this wave's first tile within the batch's 256 tiles.
    const int wtile = w * 64;
    const uint4* bpb = bfrag + ((size_t)b * 256) * 64;    // batch base
    const f32x16 zero16 = {0.f, 0.f, 0.f, 0.f, 0.f, 0.f, 0.f, 0.f,
                           0.f, 0.f, 0.f, 0.f, 0.f, 0.f, 0.f, 0.f};

    // ---- Pass A: stream minima of e = |c|^2 - 2 q.c, 8-deep prefetch ring ----
    float m0[16];
#pragma unroll
    for (int r = 0; r < 16; ++r) m0[r] = 3.4e38f;

    uint4 pf0 = bpb[(wtile + 0) * 64 + lane], pf1 = bpb[(wtile + 1) * 64 + lane];
    uint4 pf2 = bpb[(wtile + 2) * 64 + lane], pf3 = bpb[(wtile + 3) * 64 + lane];
    uint4 pf4 = bpb[(wtile + 4) * 64 + lane], pf5 = bpb[(wtile + 5) * 64 + lane];
    uint4 pf6 = bpb[(wtile + 6) * 64 + lane], pf7 = bpb[(wtile + 7) * 64 + lane];

#define STEP_A(PF, KOFF)                                                              \
    {                                                                                 \
        const bf16x8 bw = __builtin_bit_cast(bf16x8, PF);                             \
        PF = bpb[min(wtile + tb + 8 + KOFF, 255) * 64 + lane];                        \
        const f32x16 a0 = __builtin_amdgcn_mfma_f32_32x32x16_bf16(af, bw, zero16, 0, 0, 0); \
        _Pragma("unroll")                                                             \
        for (int r = 0; r < 16; ++r) m0[r] = fminf(m0[r], a0[r]);                     \
    }

    for (int tt = 0; tt < 8; ++tt) {
        const int tb = tt * 8;
        STEP_A(pf0, 0)
        STEP_A(pf1, 1)
        STEP_A(pf2, 2)
        STEP_A(pf3, 3)
        STEP_A(pf4, 4)
        STEP_A(pf5, 5)
        STEP_A(pf6, 6)
        STEP_A(pf7, 7)
    }
#undef STEP_A

    // C/D layout (verified): col=lane&31 (cand-class), row=(r&3)+8*(r>>2)+4*hi (query).
    // stream id = w*32 + col.
#pragma unroll
    for (int r = 0; r < 16; ++r) {
        const int q0 = (r & 3) + 8 * (r >> 2) + 4 * hi;
        s_minv[q0][w * 32 + col] = m0[r];
    }
    if (tid < 32) s_cnt[tid] = 0;
    __syncthreads();                                  // B1 (all 128 streams written)

    // ---- combine 128 -> 64 streams (pairwise min over disjoint candidate sets) ----
    for (int e = tid; e < 32 * 64; e += 256) {
        const int q = e >> 6, j = e & 63;
        s_minv[q][j] = fminf(s_minv[q][j], s_minv[q][64 + j]);
    }
    __syncthreads();                                  // B2

    // ---- U select: rank-15 (16th smallest) of 64 stream minima per query ----
    for (int qi = 0; qi < 8; ++qi) {
        const int q = w * 8 + qi;
        const float v = s_minv[q][lane];
        int rk = 0;
#pragma unroll 8
        for (int j = 0; j < 64; ++j) {
            const float vv = s_minv[q][j];
            rk += ((vv < v) || (vv == v && j < lane)) ? 1 : 0;
        }
        if (rk == 15) s_U[q] = v;                     // exactly one (value,stream) wins
    }
    __syncthreads();                                  // B3 (last s_minv read; s_surv may now be written)

    // ---- Pass B: gated admission ----
    float U0[16];
#pragma unroll
    for (int r = 0; r < 16; ++r) {
        const int q0 = (r & 3) + 8 * (r >> 2) + 4 * hi;
        U0[r] = s_U[q0] + SLACK;
    }

    pf0 = bpb[(wtile + 0) * 64 + lane]; pf1 = bpb[(wtile + 1) * 64 + lane];
    pf2 = bpb[(wtile + 2) * 64 + lane]; pf3 = bpb[(wtile + 3) * 64 + lane];
    pf4 = bpb[(wtile + 4) * 64 + lane]; pf5 = bpb[(wtile + 5) * 64 + lane];
    pf6 = bpb[(wtile + 6) * 64 + lane]; pf7 = bpb[(wtile + 7) * 64 + lane];

#define STEP_B(PF, KOFF)                                                              \
    {                                                                                 \
        const bf16x8 bw = __builtin_bit_cast(bf16x8, PF);                             \
        PF = bpb[min(wtile + tb + 8 + KOFF, 255) * 64 + lane];                        \
        const f32x16 a0 = __builtin_amdgcn_mfma_f32_32x32x16_bf16(af, bw, zero16, 0, 0, 0); \
        const int cand = (wtile + tb + KOFF) * 32 + col;                              \
        _Pragma("unroll")                                                             \
        for (int r = 0; r < 16; ++r) {                                                \
            if (a0[r] <= U0[r]) {                                                     \
                const int q0 = (r & 3) + 8 * (r >> 2) + 4 * hi;                       \
                const int pos = atomicAdd(&s_cnt[q0], 1);                             \
                if (pos < CAP2) s_surv[q0][pos] = cand;                               \
            }                                                                         \
        }                                                                             \
    }

    for (int tt = 0; tt < 8; ++tt) {
        const int tb = tt * 8;
        STEP_B(pf0, 0)
        STEP_B(pf1, 1)
        STEP_B(pf2, 2)
        STEP_B(pf3, 3)
        STEP_B(pf4, 4)
        STEP_B(pf5, 5)
        STEP_B(pf6, 6)
        STEP_B(pf7, 7)
    }
#undef STEP_B
    __syncthreads();                                  // B4

    // ---- Epilogue: exact distances + lex rank (verbatim semantics of proven kernel).
    // Rank loop 4-way unrolled: 8 independent broadcast LDS reads per group instead of
    // 2 dependent ones (ds_read latency ~60-120 cyc was serializing prior rounds).
    for (int qi = 0; qi < 8; ++qi) {
        const int q = w * 8 + qi;
        const int n = min(s_cnt[q], CAP2);
        const float4 qp = pb[n0 + q];
        float d1 = 3.4e38f, d2 = 3.4e38f;
        int i1 = -1, i2 = -1;
        if (lane < n) {
            i1 = s_surv[q][lane];
            const float4 v = pb[i1];
            float dot = qp.x * v.x;
            dot = fmaf(qp.y, v.y, dot);
            dot = fmaf(qp.z, v.z, dot);
            d1 = fmaf(dot, -2.0f, qp.w + v.w);        // identical rounding to reference path
        }
        if (64 + lane < n) {
            i2 = s_surv[q][64 + lane];
            const float4 v = pb[i2];
            float dot = qp.x * v.x;
            dot = fmaf(qp.y, v.y, dot);
            dot = fmaf(qp.z, v.z, dot);
            d2 = fmaf(dot, -2.0f, qp.w + v.w);
        }
        s_rd[w][lane] = d1;      s_ri[w][lane] = i1;
        s_rd[w][64 + lane] = d2; s_ri[w][64 + lane] = i2;
        asm volatile("s_waitcnt lgkmcnt(0)" ::: "memory");   // in-wave LDS producer/consumer
        __builtin_amdgcn_wave_barrier();
        int r1 = 0, r2 = 0;
        int k = 0;
        for (; k + 3 < n; k += 4) {
            const float dk0 = s_rd[w][k + 0], dk1 = s_rd[w][k + 1];
            const float dk2 = s_rd[w][k + 2], dk3 = s_rd[w][k + 3];
            const int   ik0 = s_ri[w][k + 0], ik1 = s_ri[w][k + 1];
            const int   ik2 = s_ri[w][k + 2], ik3 = s_ri[w][k + 3];
            r1 += (lex_lt(dk0, ik0, d1, i1) ? 1 : 0) + (lex_lt(dk1, ik1, d1, i1) ? 1 : 0)
                + (lex_lt(dk2, ik2, d1, i1) ? 1 : 0) + (lex_lt(dk3, ik3, d1, i1) ? 1 : 0);
            r2 += (lex_lt(dk0, ik0, d2, i2) ? 1 : 0) + (lex_lt(dk1, ik1, d2, i2) ? 1 : 0)
                + (lex_lt(dk2, ik2, d2, i2) ? 1 : 0) + (lex_lt(dk3, ik3, d2, i2) ? 1 : 0);
        }
        for (; k < n; ++k) {
            const float dk = s_rd[w][k];
            const int   ik = s_ri[w][k];
            r1 += lex_lt(dk, ik, d1, i1) ? 1 : 0;
            r2 += lex_lt(dk, ik, d2, i2) ? 1 : 0;
        }
        if (lane < n && r1 < KNN)      idx_out[(size_t)(qbase + q) * KNN + r1] = i1;
        if (64 + lane < n && r2 < KNN) idx_out[(size_t)(qbase + q) * KNN + r2] = i2;
        __builtin_amdgcn_wave_barrier();              // scratch WAR across queries (in-wave)
    }
}

// ---------------- Kernel 2: MFMA agg — one wave per point, hi/lo bf16 (r11-proven) ----
#define MIDP 132   // s_mid leading-dim pad: 128 -> 132 breaks bank-aligned row stride
__global__ __launch_bounds__(256) void agg_kernel(
    const float* __restrict__ pts,
    const float* __restrict__ feat,
    const float* __restrict__ w_geom,
    const float* __restrict__ g1, const float* __restrict__ b1,
    const float* __restrict__ m1, const float* __restrict__ v1,
    const float* __restrict__ w_sem,
    const float* __restrict__ g2, const float* __restrict__ b2,
    const float* __restrict__ m2, const float* __restrict__ v2,
    const float* __restrict__ w_fuse,
    const float* __restrict__ g3, const float* __restrict__ b3,
    const float* __restrict__ m3, const float* __restrict__ v3,
    const int* __restrict__ knn_idx,
    float* __restrict__ outp) {

    __shared__ alignas(16) unsigned short s_wsemB[8192];    // 16 frags x 64 lanes x 8 bf16
    __shared__ alignas(16) unsigned short s_wfuseB[8192];
    __shared__ float s_wg[6][64];
    __shared__ float s_s1[64], s_b1[64], s_s2[64], s_b2[64], s_s3[64], s_b3[64];
    __shared__ alignas(16) float s_mid[4][16][MIDP];
    __shared__ float s_pm[4][4][64];
    __shared__ alignas(16) float s_ctrf[4][64];
    __shared__ float s_gd[4][16][4];
    __shared__ int   s_nidx[4][16];
    __shared__ float s_ctrp[4][4];

    const int tid = threadIdx.x;
    const int w = tid >> 6, lane = tid & 63;
    const int r = lane & 15, qd = lane >> 4;

    for (int e = tid; e < 1024; e += 256) {          // e = (kc*4+n0)*64 + ln
        const int ln = e & 63;
        const int o = ((e >> 6) & 3) * 16 + (ln & 15);
        const int c = (e >> 8) * 32 + (ln >> 4) * 8;
        unsigned short ts[8], tf[8];
#pragma unroll
        for (int j = 0; j < 8; ++j) {
            ts[j] = f2bf(w_sem [o * 128 + c + j]);
            tf[j] = f2bf(w_fuse[o * 128 + c + j]);
        }
        *(uint4*)&s_wsemB [e * 8] = *(uint4*)ts;
        *(uint4*)&s_wfuseB[e * 8] = *(uint4*)tf;
    }
    for (int e = tid; e < 384; e += 256) {
        const int c = e >> 6, o = e & 63;
        s_wg[c][o] = w_geom[o * 6 + c];
    }
    if (tid < 64) {
        float s;
        s = g1[tid] / sqrtf(v1[tid] + 1e-5f);
        s_s1[tid] = s; s_b1[tid] = b1[tid] - m1[tid] * s;
        s = g2[tid] / sqrtf(v2[tid] + 1e-5f);
        s_s2[tid] = s; s_b2[tid] = b2[tid] - m2[tid] * s;
        s = g3[tid] / sqrtf(v3[tid] + 1e-5f);
        s_s3[tid] = s; s_b3[tid] = b3[tid] - m3[tid] * s;
    }
    __syncthreads();

    const f32x4 zero = {0.f, 0.f, 0.f, 0.f};

    for (int i = 0; i < 4; ++i) {
        const int pv = blockIdx.x * 16 + w * 4 + i;
        const int b = pv >> 13, n = pv & (NPTS - 1);
        const long pbase = (long)b * NPTS + n;

        if (lane < 16) s_nidx[w][lane] = knn_idx[pbase * KNN + lane];
        s_ctrf[w][lane] = feat[pbase * CH + lane];
        if (lane < 3) s_ctrp[w][lane] = pts[pbase * 3 + lane];
        __syncthreads();                                       // B1

        if (lane < 16) {
            const long nb = (long)b * NPTS + s_nidx[w][lane];
            s_gd[w][lane][0] = pts[nb * 3 + 0] - s_ctrp[w][0];
            s_gd[w][lane][1] = pts[nb * 3 + 1] - s_ctrp[w][1];
            s_gd[w][lane][2] = pts[nb * 3 + 2] - s_ctrp[w][2];
        }

        bf16x8 ah[4], al[4];
        {
            float xs[8];
#pragma unroll
            for (int kc = 0; kc < 2; ++kc) {
#pragma unroll
                for (int j = 0; j < 8; ++j) xs[j] = s_ctrf[w][kc * 32 + qd * 8 + j];
                split8(xs, ah[kc], al[kc]);
            }
            const long nb = (long)b * NPTS + s_nidx[w][r];
            const float* fp = feat + nb * CH;
#pragma unroll
            for (int kc = 0; kc < 2; ++kc) {
                const int base = kc * 32 + qd * 8;
                const float4 v0 = *(const float4*)(fp + base);
                const float4 v1 = *(const float4*)(fp + base + 4);
                xs[0] = v0.x - s_ctrf[w][base + 0];
                xs[1] = v0.y - s_ctrf[w][base + 1];
                xs[2] = v0.z - s_ctrf[w][base + 2];
                xs[3] = v0.w - s_ctrf[w][base + 3];
                xs[4] = v1.x - s_ctrf[w][base + 4];
                xs[5] = v1.y - s_ctrf[w][base + 5];
                xs[6] = v1.z - s_ctrf[w][base + 6];
                xs[7] = v1.w - s_ctrf[w][base + 7];
                split8(xs, ah[2 + kc], al[2 + kc]);
            }
        }
        f32x4 acc[4] = {zero, zero, zero, zero};
#pragma unroll
        for (int kc = 0; kc < 4; ++kc) {
#pragma unroll
            for (int n0 = 0; n0 < 4; ++n0) {
                const bf16x8 bw = *(const bf16x8*)&s_wsemB[((kc * 4 + n0) * 64 + lane) * 8];
                acc[n0] = __builtin_amdgcn_mfma_f32_16x16x32_bf16(ah[kc], bw, acc[n0], 0, 0, 0);
                acc[n0] = __builtin_amdgcn_mfma_f32_16x16x32_bf16(al[kc], bw, acc[n0], 0, 0, 0);
            }
        }
#pragma unroll
        for (int n0 = 0; n0 < 4; ++n0) {
            const int nn = n0 * 16 + r;
            const float sv = s_s2[nn], bv = s_b2[nn];
#pragma unroll
            for (int reg = 0; reg < 4; ++reg) {
                s_mid[w][qd * 4 + reg][64 + nn] = fmaxf(fmaf(acc[n0][reg], sv, bv), 0.f);
            }
        }
        __syncthreads();                                       // B2 (s_gd ready)

        {
            const int o = lane;
            float cg = s_ctrp[w][0] * s_wg[0][o];
            cg = fmaf(s_ctrp[w][1], s_wg[1][o], cg);
            cg = fmaf(s_ctrp[w][2], s_wg[2][o], cg);
            const float s1o = s_s1[o], b1o = s_b1[o];
#pragma unroll
            for (int r2 = 0; r2 < 16; ++r2) {
                float g = cg;
                g = fmaf(s_gd[w][r2][0], s_wg[3][o], g);
                g = fmaf(s_gd[w][r2][1], s_wg[4][o], g);
                g = fmaf(s_gd[w][r2][2], s_wg[5][o], g);
                s_mid[w][r2][o] = fmaxf(fmaf(g, s1o, b1o), 0.f);
            }
        }
        __syncthreads();                                       // B3 (mid complete)

        bf16x8 fh[4], fl[4];
        {
            float xs[8];
#pragma unroll
            for (int kc = 0; kc < 4; ++kc) {
                const float* mp = &s_mid[w][r][kc * 32 + qd * 8];
#pragma unroll
                for (int j = 0; j < 8; ++j) xs[j] = mp[j];
                split8(xs, fh[kc], fl[kc]);
            }
        }
        f32x4 acc2[4] = {zero, zero, zero, zero};
#pragma unroll
        for (int kc = 0; kc < 4; ++kc) {
#pragma unroll
            for (int n0 = 0; n0 < 4; ++n0) {
                const bf16x8 bw = *(const bf16x8*)&s_wfuseB[((kc * 4 + n0) * 64 + lane) * 8];
                acc2[n0] = __builtin_amdgcn_mfma_f32_16x16x32_bf16(fh[kc], bw, acc2[n0], 0, 0, 0);
                acc2[n0] = __builtin_amdgcn_mfma_f32_16x16x32_bf16(fl[kc], bw, acc2[n0], 0, 0, 0);
            }
        }
#pragma unroll
        for (int n0 = 0; n0 < 4; ++n0) {
            const int nn = n0 * 16 + r;
            const float sv = s_s3[nn], bv = s_b3[nn];
            float mx = 0.f;   // relu outputs >= 0
#pragma unroll
            for (int reg = 0; reg < 4; ++reg)
                mx = fmaxf(mx, fmaxf(fmaf(acc2[n0][reg], sv, bv), 0.f));
            s_pm[w][qd][nn] = mx;
        }
        __syncthreads();                                       // B4
        {
            const int o = lane;
            const float rv = fmaxf(fmaxf(s_pm[w][0][o], s_pm[w][1][o]),
                                   fmaxf(s_pm[w][2][o], s_pm[w][3][o]));
            outp[pbase * CH + o] = rv;
        }
        __syncthreads();                                       // B5 (WAR across iters)
    }
}

extern "C" void kernel_launch(void* const* d_in, const int* in_sizes, int n_in,
                              void* d_out, int out_size, void* d_ws, size_t ws_size,
                              hipStream_t stream) {
    (void)in_sizes; (void)n_in; (void)out_size; (void)ws_size;
    const float* pts    = (const float*)d_in[0];
    const float* feat   = (const float*)d_in[1];
    const float* w_geom = (const float*)d_in[2];
    const float* g1     = (const float*)d_in[3];
    const float* b1     = (const float*)d_in[4];
    const float* m1     = (const float*)d_in[5];
    const float* v1     = (const float*)d_in[6];
    const float* w_sem  = (const float*)d_in[7];
    const float* g2     = (const float*)d_in[8];
    const float* b2     = (const float*)d_in[9];
    const float* m2     = (const float*)d_in[10];
    const float* v2     = (const float*)d_in[11];
    const float* w_fuse = (const float*)d_in[12];
    const float* g3     = (const float*)d_in[13];
    const float* b3     = (const float*)d_in[14];
    const float* m3     = (const float*)d_in[15];
    const float* v3     = (const float*)d_in[16];

    int*    idx_final = (int*)d_ws;                             // 2 MB @ 0
    uint4*  bfrag     = (uint4*)((char*)d_ws + (2ull << 20));   // 1 MB @ 2MB
    float4* pts4      = (float4*)((char*)d_ws + (4ull << 20));  // 512 KB @ 4MB

    pack_kernel<<<dim3(NB * NPTS / 256), dim3(256), 0, stream>>>(pts, pts4, bfrag);
    knn_mfma_kernel<<<dim3(NB * NPTS / 32), dim3(256), 0, stream>>>(pts4, bfrag, idx_final);

    agg_kernel<<<dim3(2048), dim3(256), 0, stream>>>(
        pts, feat, w_geom, g1, b1, m1, v1, w_sem, g2, b2, m2, v2,
        w_fuse, g3, b3, m3, v3, idx_final, (float*)d_out);
}

// Round 6
// 249.444 us; speedup vs baseline: 1.3554x; 1.0605x over previous
//
#include <hip/hip_runtime.h>

#define NPTS 8192
#define NB 4
#define CH 64
#define KNN 16
#define CAP2 128          // survivors per query (expected ~20-40; passed rounds at 128)
#define SLACK 4e-3f       // > 2*eps of bf16 hi/lo MFMA distance approx (eps ~ 5e-4)
#define MNVP 129          // s_minv pad: 129 % 32 = 1 -> conflict-free column reads

using bf16x8 = __attribute__((ext_vector_type(8))) __bf16;
using us8    = __attribute__((ext_vector_type(8))) unsigned short;
using f32x4  = __attribute__((ext_vector_type(4))) float;
using f32x16 = __attribute__((ext_vector_type(16))) float;

__device__ __forceinline__ float bf2f(unsigned short u) {
    return __uint_as_float(((unsigned)u) << 16);
}
__device__ __forceinline__ unsigned short f2bf(float f) {
    unsigned u = __float_as_uint(f);
    u += 0x7fffu + ((u >> 16) & 1u);
    return (unsigned short)(u >> 16);
}

// split 8 f32 into hi/lo bf16: x = hi + lo. Native casts -> v_cvt_pk_bf16_f32 (RNE,
// bit-identical to the manual round-to-nearest-even f2bf) at ~1/2 the VALU ops.
__device__ __forceinline__ void split8(const float* x, bf16x8& hi, bf16x8& lo) {
#pragma unroll
    for (int j = 0; j < 8; ++j) {
        const __bf16 h = (__bf16)x[j];
        hi[j] = h;
        lo[j] = (__bf16)(x[j] - (float)h);
    }
}

// in-wave LDS fence: order prior LDS writes before subsequent reads, no cross-wave stall
__device__ __forceinline__ void wave_fence() {
    asm volatile("s_waitcnt lgkmcnt(0)" ::: "memory");
    __builtin_amdgcn_wave_barrier();
}

// lexicographic (d,i) compare: true if (dB,iB) < (dA,iA)
__device__ __forceinline__ bool lex_lt(float dB, int iB, float dA, int iA) {
    return (dB < dA) || ((dB == dA) && (iB < iA));
}

// ---------------- Kernel 0: pack {x,y,z,sq} + 32x32x16 MFMA B-fragments --------------
// (frozen, passed rounds 3/5)
__global__ __launch_bounds__(256) void pack_kernel(const float* __restrict__ pts,
                                                   float4* __restrict__ pts4,
                                                   uint4* __restrict__ bfrag) {
    const int i = blockIdx.x * 256 + threadIdx.x;   // 0..32767
    const float x = pts[i * 3 + 0];
    const float y = pts[i * 3 + 1];
    const float z = pts[i * 3 + 2];
    const float sq = (x * x + y * y) + z * z;       // reference-path formula
    pts4[i] = make_float4(x, y, z, sq);

    const float sx = -2.f * x, sy = -2.f * y, sz = -2.f * z;
    const unsigned short shx = f2bf(sx), shy = f2bf(sy), shz = f2bf(sz);
    const unsigned short slx = f2bf(sx - bf2f(shx));
    const unsigned short sly = f2bf(sy - bf2f(shy));
    const unsigned short slz = f2bf(sz - bf2f(shz));
    const unsigned short sqh = f2bf(sq), sql = f2bf(sq - bf2f(sqh));

    const int b = i >> 13, n = i & (NPTS - 1);
    const int tile = n >> 5, col = n & 31;
    uint4* base = bfrag + ((size_t)(b * 256 + tile)) * 64;

    unsigned short g0[8], g1[8];
    g0[0] = shx; g0[1] = shy; g0[2] = shz; g0[3] = slx;
    g0[4] = sly; g0[5] = slz; g0[6] = shx; g0[7] = shy;   // k0..7
    g1[0] = shz; g1[1] = slx; g1[2] = sly; g1[3] = slz;
    g1[4] = sqh; g1[5] = sql; g1[6] = 0;   g1[7] = 0;     // k8..15
    base[col]      = *(const uint4*)g0;
    base[32 + col] = *(const uint4*)g1;
}

// A-fragment for one query point, k-half kh = lane>>5 (proven k-plan)
__device__ __forceinline__ bf16x8 make_afrag(const float4 qp, const int kh) {
    const unsigned short hx = f2bf(qp.x), hy = f2bf(qp.y), hz = f2bf(qp.z);
    const unsigned short lx = f2bf(qp.x - bf2f(hx));
    const unsigned short ly = f2bf(qp.y - bf2f(hy));
    const unsigned short lz = f2bf(qp.z - bf2f(hz));
    us8 u;
#pragma unroll
    for (int j = 0; j < 8; ++j) u[j] = 0;
    if (kh == 0) {
        u[0] = hx; u[1] = hy; u[2] = hz; u[3] = hx;
        u[4] = hy; u[5] = hz; u[6] = lx; u[7] = ly;       // k0..7
    } else {
        u[0] = lz; u[1] = lx; u[2] = ly; u[3] = lz;
        u[4] = 0x3f80u; u[5] = 0x3f80u;                   // 1.0 * sq_hi/lo, k8..15
    }
    return __builtin_bit_cast(bf16x8, u);
}

// ---------------- Kernel 1: MFMA KNN (frozen, passed round 5) ------------------------
__global__ __launch_bounds__(256, 4) void knn_mfma_kernel(const float4* __restrict__ pts4,
                                                          const uint4* __restrict__ bfrag,
                                                          int* __restrict__ idx_out) {
    __shared__ alignas(16) char s_union[32 * MNVP * 4];   // 16,512 B
    float (*s_minv)[MNVP] = (float(*)[MNVP])s_union;      // [32][129], dead after B3
    int   (*s_surv)[CAP2] = (int(*)[CAP2])s_union;        // [32][128], written after B3
    __shared__ float s_U[32];
    __shared__ int   s_cnt[32];
    __shared__ float s_rd[4][CAP2];
    __shared__ int   s_ri[4][CAP2];

    const int tid  = threadIdx.x;
    const int w    = tid >> 6, lane = tid & 63;
    const int col  = lane & 31, hi = lane >> 5;
    const int qbase = blockIdx.x * 32;               // global query id (= b*8192 + n0)
    const int b = qbase >> 13, n0 = qbase & (NPTS - 1);
    const float4* pb = pts4 + (size_t)b * NPTS;

    // A-fragment: rows = queries n0..n0+31
    const bf16x8 af = make_afrag(pb[n0 + col], hi);

    const int wtile = w * 64;
    const uint4* bpb = bfrag + ((size_t)b * 256) * 64;    // batch base
    const f32x16 zero16 = {0.f, 0.f, 0.f, 0.f, 0.f, 0.f, 0.f, 0.f,
                           0.f, 0.f, 0.f, 0.f, 0.f, 0.f, 0.f, 0.f};

    // ---- Pass A: stream minima of e = |c|^2 - 2 q.c, 8-deep prefetch ring ----
    float m0[16];
#pragma unroll
    for (int r = 0; r < 16; ++r) m0[r] = 3.4e38f;

    uint4 pf0 = bpb[(wtile + 0) * 64 + lane], pf1 = bpb[(wtile + 1) * 64 + lane];
    uint4 pf2 = bpb[(wtile + 2) * 64 + lane], pf3 = bpb[(wtile + 3) * 64 + lane];
    uint4 pf4 = bpb[(wtile + 4) * 64 + lane], pf5 = bpb[(wtile + 5) * 64 + lane];
    uint4 pf6 = bpb[(wtile + 6) * 64 + lane], pf7 = bpb[(wtile + 7) * 64 + lane];

#define STEP_A(PF, KOFF)                                                              \
    {                                                                                 \
        const bf16x8 bw = __builtin_bit_cast(bf16x8, PF);                             \
        PF = bpb[min(wtile + tb + 8 + KOFF, 255) * 64 + lane];                        \
        const f32x16 a0 = __builtin_amdgcn_mfma_f32_32x32x16_bf16(af, bw, zero16, 0, 0, 0); \
        _Pragma("unroll")                                                             \
        for (int r = 0; r < 16; ++r) m0[r] = fminf(m0[r], a0[r]);                     \
    }

    for (int tt = 0; tt < 8; ++tt) {
        const int tb = tt * 8;
        STEP_A(pf0, 0)
        STEP_A(pf1, 1)
        STEP_A(pf2, 2)
        STEP_A(pf3, 3)
        STEP_A(pf4, 4)
        STEP_A(pf5, 5)
        STEP_A(pf6, 6)
        STEP_A(pf7, 7)
    }
#undef STEP_A

    // C/D layout (verified): col=lane&31 (cand-class), row=(r&3)+8*(r>>2)+4*hi (query).
#pragma unroll
    for (int r = 0; r < 16; ++r) {
        const int q0 = (r & 3) + 8 * (r >> 2) + 4 * hi;
        s_minv[q0][w * 32 + col] = m0[r];
    }
    if (tid < 32) s_cnt[tid] = 0;
    __syncthreads();                                  // B1 (all 128 streams written)

    // ---- combine 128 -> 64 streams (pairwise min over disjoint candidate sets) ----
    for (int e = tid; e < 32 * 64; e += 256) {
        const int q = e >> 6, j = e & 63;
        s_minv[q][j] = fminf(s_minv[q][j], s_minv[q][64 + j]);
    }
    __syncthreads();                                  // B2

    // ---- U select: rank-15 (16th smallest) of 64 stream minima per query ----
    for (int qi = 0; qi < 8; ++qi) {
        const int q = w * 8 + qi;
        const float v = s_minv[q][lane];
        int rk = 0;
#pragma unroll 8
        for (int j = 0; j < 64; ++j) {
            const float vv = s_minv[q][j];
            rk += ((vv < v) || (vv == v && j < lane)) ? 1 : 0;
        }
        if (rk == 15) s_U[q] = v;                     // exactly one (value,stream) wins
    }
    __syncthreads();                                  // B3

    // ---- Pass B: gated admission ----
    float U0[16];
#pragma unroll
    for (int r = 0; r < 16; ++r) {
        const int q0 = (r & 3) + 8 * (r >> 2) + 4 * hi;
        U0[r] = s_U[q0] + SLACK;
    }

    pf0 = bpb[(wtile + 0) * 64 + lane]; pf1 = bpb[(wtile + 1) * 64 + lane];
    pf2 = bpb[(wtile + 2) * 64 + lane]; pf3 = bpb[(wtile + 3) * 64 + lane];
    pf4 = bpb[(wtile + 4) * 64 + lane]; pf5 = bpb[(wtile + 5) * 64 + lane];
    pf6 = bpb[(wtile + 6) * 64 + lane]; pf7 = bpb[(wtile + 7) * 64 + lane];

#define STEP_B(PF, KOFF)                                                              \
    {                                                                                 \
        const bf16x8 bw = __builtin_bit_cast(bf16x8, PF);                             \
        PF = bpb[min(wtile + tb + 8 + KOFF, 255) * 64 + lane];                        \
        const f32x16 a0 = __builtin_amdgcn_mfma_f32_32x32x16_bf16(af, bw, zero16, 0, 0, 0); \
        const int cand = (wtile + tb + KOFF) * 32 + col;                              \
        _Pragma("unroll")                                                             \
        for (int r = 0; r < 16; ++r) {                                                \
            if (a0[r] <= U0[r]) {                                                     \
                const int q0 = (r & 3) + 8 * (r >> 2) + 4 * hi;                       \
                const int pos = atomicAdd(&s_cnt[q0], 1);                             \
                if (pos < CAP2) s_surv[q0][pos] = cand;                               \
            }                                                                         \
        }                                                                             \
    }

    for (int tt = 0; tt < 8; ++tt) {
        const int tb = tt * 8;
        STEP_B(pf0, 0)
        STEP_B(pf1, 1)
        STEP_B(pf2, 2)
        STEP_B(pf3, 3)
        STEP_B(pf4, 4)
        STEP_B(pf5, 5)
        STEP_B(pf6, 6)
        STEP_B(pf7, 7)
    }
#undef STEP_B
    __syncthreads();                                  // B4

    // ---- Epilogue: exact distances + lex rank (byte-identical semantics) ----
    for (int qi = 0; qi < 8; ++qi) {
        const int q = w * 8 + qi;
        const int n = min(s_cnt[q], CAP2);
        const float4 qp = pb[n0 + q];
        float d1 = 3.4e38f, d2 = 3.4e38f;
        int i1 = -1, i2 = -1;
        if (lane < n) {
            i1 = s_surv[q][lane];
            const float4 v = pb[i1];
            float dot = qp.x * v.x;
            dot = fmaf(qp.y, v.y, dot);
            dot = fmaf(qp.z, v.z, dot);
            d1 = fmaf(dot, -2.0f, qp.w + v.w);        // identical rounding to reference path
        }
        if (64 + lane < n) {
            i2 = s_surv[q][64 + lane];
            const float4 v = pb[i2];
            float dot = qp.x * v.x;
            dot = fmaf(qp.y, v.y, dot);
            dot = fmaf(qp.z, v.z, dot);
            d2 = fmaf(dot, -2.0f, qp.w + v.w);
        }
        s_rd[w][lane] = d1;      s_ri[w][lane] = i1;
        s_rd[w][64 + lane] = d2; s_ri[w][64 + lane] = i2;
        asm volatile("s_waitcnt lgkmcnt(0)" ::: "memory");   // in-wave LDS producer/consumer
        __builtin_amdgcn_wave_barrier();
        int r1 = 0, r2 = 0;
        int k = 0;
        for (; k + 3 < n; k += 4) {
            const float dk0 = s_rd[w][k + 0], dk1 = s_rd[w][k + 1];
            const float dk2 = s_rd[w][k + 2], dk3 = s_rd[w][k + 3];
            const int   ik0 = s_ri[w][k + 0], ik1 = s_ri[w][k + 1];
            const int   ik2 = s_ri[w][k + 2], ik3 = s_ri[w][k + 3];
            r1 += (lex_lt(dk0, ik0, d1, i1) ? 1 : 0) + (lex_lt(dk1, ik1, d1, i1) ? 1 : 0)
                + (lex_lt(dk2, ik2, d1, i1) ? 1 : 0) + (lex_lt(dk3, ik3, d1, i1) ? 1 : 0);
            r2 += (lex_lt(dk0, ik0, d2, i2) ? 1 : 0) + (lex_lt(dk1, ik1, d2, i2) ? 1 : 0)
                + (lex_lt(dk2, ik2, d2, i2) ? 1 : 0) + (lex_lt(dk3, ik3, d2, i2) ? 1 : 0);
        }
        for (; k < n; ++k) {
            const float dk = s_rd[w][k];
            const int   ik = s_ri[w][k];
            r1 += lex_lt(dk, ik, d1, i1) ? 1 : 0;
            r2 += lex_lt(dk, ik, d2, i2) ? 1 : 0;
        }
        if (lane < n && r1 < KNN)      idx_out[(size_t)(qbase + q) * KNN + r1] = i1;
        if (64 + lane < n && r2 < KNN) idx_out[(size_t)(qbase + q) * KNN + r2] = i2;
        __builtin_amdgcn_wave_barrier();              // scratch WAR across queries (in-wave)
    }
}

// ---------------- Kernel 2: MFMA agg — wave-decoupled (no per-iter __syncthreads) ----
// All per-iteration LDS (s_mid[w], s_pm[w], s_gd[w]) is wave-private: in-wave
// lgkmcnt fences replace the 5 global barriers. Center features/coords/indices read
// directly from global (same values, same arithmetic as the former LDS staging).
#define MIDP 132   // s_mid leading-dim pad: 128 -> 132 breaks bank-aligned row stride
__global__ __launch_bounds__(256) void agg_kernel(
    const float* __restrict__ pts,
    const float* __restrict__ feat,
    const float* __restrict__ w_geom,
    const float* __restrict__ g1, const float* __restrict__ b1,
    const float* __restrict__ m1, const float* __restrict__ v1,
    const float* __restrict__ w_sem,
    const float* __restrict__ g2, const float* __restrict__ b2,
    const float* __restrict__ m2, const float* __restrict__ v2,
    const float* __restrict__ w_fuse,
    const float* __restrict__ g3, const float* __restrict__ b3,
    const float* __restrict__ m3, const float* __restrict__ v3,
    const int* __restrict__ knn_idx,
    float* __restrict__ outp) {

    __shared__ alignas(16) unsigned short s_wsemB[8192];    // 16 frags x 64 lanes x 8 bf16
    __shared__ alignas(16) unsigned short s_wfuseB[8192];
    __shared__ float s_wg[6][64];
    __shared__ float s_s1[64], s_b1[64], s_s2[64], s_b2[64], s_s3[64], s_b3[64];
    __shared__ alignas(16) float s_mid[4][16][MIDP];
    __shared__ float s_pm[4][4][64];
    __shared__ float s_gd[4][16][4];

    const int tid = threadIdx.x;
    const int w = tid >> 6, lane = tid & 63;
    const int r = lane & 15, qd = lane >> 4;

    for (int e = tid; e < 1024; e += 256) {          // e = (kc*4+n0)*64 + ln
        const int ln = e & 63;
        const int o = ((e >> 6) & 3) * 16 + (ln & 15);
        const int c = (e >> 8) * 32 + (ln >> 4) * 8;
        unsigned short ts[8], tf[8];
#pragma unroll
        for (int j = 0; j < 8; ++j) {
            ts[j] = f2bf(w_sem [o * 128 + c + j]);
            tf[j] = f2bf(w_fuse[o * 128 + c + j]);
        }
        *(uint4*)&s_wsemB [e * 8] = *(uint4*)ts;
        *(uint4*)&s_wfuseB[e * 8] = *(uint4*)tf;
    }
    for (int e = tid; e < 384; e += 256) {
        const int c = e >> 6, o = e & 63;
        s_wg[c][o] = w_geom[o * 6 + c];
    }
    if (tid < 64) {
        float s;
        s = g1[tid] / sqrtf(v1[tid] + 1e-5f);
        s_s1[tid] = s; s_b1[tid] = b1[tid] - m1[tid] * s;
        s = g2[tid] / sqrtf(v2[tid] + 1e-5f);
        s_s2[tid] = s; s_b2[tid] = b2[tid] - m2[tid] * s;
        s = g3[tid] / sqrtf(v3[tid] + 1e-5f);
        s_s3[tid] = s; s_b3[tid] = b3[tid] - m3[tid] * s;
    }
    __syncthreads();   // ONLY global barrier: weight staging

    const f32x4 zero = {0.f, 0.f, 0.f, 0.f};

    const int pv0 = blockIdx.x * 16 + w * 4;
    // prefetch point 0's index + center coords
    int nidx_nx;
    float cpx_nx, cpy_nx, cpz_nx;
    {
        const int b = pv0 >> 13, n = pv0 & (NPTS - 1);
        const long pbase = (long)b * NPTS + n;
        nidx_nx = knn_idx[pbase * KNN + r];
        cpx_nx = pts[pbase * 3 + 0];
        cpy_nx = pts[pbase * 3 + 1];
        cpz_nx = pts[pbase * 3 + 2];
    }

#pragma unroll
    for (int i = 0; i < 4; ++i) {
        const int pv = pv0 + i;
        const int b = pv >> 13, n = pv & (NPTS - 1);
        const long pbase = (long)b * NPTS + n;
        const int   nidx_r = nidx_nx;                 // this lane's MFMA-row neighbor
        const float cpx = cpx_nx, cpy = cpy_nx, cpz = cpz_nx;
        const long  nb = (long)b * NPTS + nidx_r;

        if (lane < 16) {                              // r == lane here
            s_gd[w][lane][0] = pts[nb * 3 + 0] - cpx;
            s_gd[w][lane][1] = pts[nb * 3 + 1] - cpy;
            s_gd[w][lane][2] = pts[nb * 3 + 2] - cpz;
        }

        // A-fragments: center features + (neighbor - center), direct global loads
        bf16x8 ah[4], al[4];
        {
            const float* cf = feat + pbase * CH;
            const float* fp = feat + nb * CH;
            float xs[8];
#pragma unroll
            for (int kc = 0; kc < 2; ++kc) {
                const int base = kc * 32 + qd * 8;
                const float4 c0 = *(const float4*)(cf + base);
                const float4 c1 = *(const float4*)(cf + base + 4);
                const float4 v0 = *(const float4*)(fp + base);
                const float4 v1 = *(const float4*)(fp + base + 4);
                xs[0] = c0.x; xs[1] = c0.y; xs[2] = c0.z; xs[3] = c0.w;
                xs[4] = c1.x; xs[5] = c1.y; xs[6] = c1.z; xs[7] = c1.w;
                split8(xs, ah[kc], al[kc]);
                xs[0] = v0.x - c0.x; xs[1] = v0.y - c0.y;
                xs[2] = v0.z - c0.z; xs[3] = v0.w - c0.w;
                xs[4] = v1.x - c1.x; xs[5] = v1.y - c1.y;
                xs[6] = v1.z - c1.z; xs[7] = v1.w - c1.w;
                split8(xs, ah[2 + kc], al[2 + kc]);
            }
        }
        f32x4 acc[4] = {zero, zero, zero, zero};
#pragma unroll
        for (int kc = 0; kc < 4; ++kc) {
#pragma unroll
            for (int n0 = 0; n0 < 4; ++n0) {
                const bf16x8 bw = *(const bf16x8*)&s_wsemB[((kc * 4 + n0) * 64 + lane) * 8];
                acc[n0] = __builtin_amdgcn_mfma_f32_16x16x32_bf16(ah[kc], bw, acc[n0], 0, 0, 0);
                acc[n0] = __builtin_amdgcn_mfma_f32_16x16x32_bf16(al[kc], bw, acc[n0], 0, 0, 0);
            }
        }
#pragma unroll
        for (int n0 = 0; n0 < 4; ++n0) {
            const int nn = n0 * 16 + r;
            const float sv = s_s2[nn], bv = s_b2[nn];
#pragma unroll
            for (int reg = 0; reg < 4; ++reg) {
                s_mid[w][qd * 4 + reg][64 + nn] = fmaxf(fmaf(acc[n0][reg], sv, bv), 0.f);
            }
        }

        // prefetch next point's idx + center coords (overlaps geom/fuse below)
        if (i < 3) {
            const int pvn = pv + 1;
            const int bn = pvn >> 13, nn2 = pvn & (NPTS - 1);
            const long pbn = (long)bn * NPTS + nn2;
            nidx_nx = knn_idx[pbn * KNN + r];
            cpx_nx = pts[pbn * 3 + 0];
            cpy_nx = pts[pbn * 3 + 1];
            cpz_nx = pts[pbn * 3 + 2];
        }

        wave_fence();                                 // F1: s_gd (and sem-mid) visible

        {
            const int o = lane;
            float cg = cpx * s_wg[0][o];
            cg = fmaf(cpy, s_wg[1][o], cg);
            cg = fmaf(cpz, s_wg[2][o], cg);
            const float s1o = s_s1[o], b1o = s_b1[o];
#pragma unroll
            for (int r2 = 0; r2 < 16; ++r2) {
                float g = cg;
                g = fmaf(s_gd[w][r2][0], s_wg[3][o], g);
                g = fmaf(s_gd[w][r2][1], s_wg[4][o], g);
                g = fmaf(s_gd[w][r2][2], s_wg[5][o], g);
                s_mid[w][r2][o] = fmaxf(fmaf(g, s1o, b1o), 0.f);
            }
        }
        wave_fence();                                 // F2: mid complete (geom+sem)

        bf16x8 fh[4], fl[4];
        {
            float xs[8];
#pragma unroll
            for (int kc = 0; kc < 4; ++kc) {
                const float* mp = &s_mid[w][r][kc * 32 + qd * 8];
#pragma unroll
                for (int j = 0; j < 8; ++j) xs[j] = mp[j];
                split8(xs, fh[kc], fl[kc]);
            }
        }
        f32x4 acc2[4] = {zero, zero, zero, zero};
#pragma unroll
        for (int kc = 0; kc < 4; ++kc) {
#pragma unroll
            for (int n0 = 0; n0 < 4; ++n0) {
                const bf16x8 bw = *(const bf16x8*)&s_wfuseB[((kc * 4 + n0) * 64 + lane) * 8];
                acc2[n0] = __builtin_amdgcn_mfma_f32_16x16x32_bf16(fh[kc], bw, acc2[n0], 0, 0, 0);
                acc2[n0] = __builtin_amdgcn_mfma_f32_16x16x32_bf16(fl[kc], bw, acc2[n0], 0, 0, 0);
            }
        }
#pragma unroll
        for (int n0 = 0; n0 < 4; ++n0) {
            const int nn = n0 * 16 + r;
            const float sv = s_s3[nn], bv = s_b3[nn];
            float mx = 0.f;   // relu outputs >= 0
#pragma unroll
            for (int reg = 0; reg < 4; ++reg)
                mx = fmaxf(mx, fmaxf(fmaf(acc2[n0][reg], sv, bv), 0.f));
            s_pm[w][qd][nn] = mx;
        }
        wave_fence();                                 // F3: pm visible
        {
            const int o = lane;
            const float rv = fmaxf(fmaxf(s_pm[w][0][o], s_pm[w][1][o]),
                                   fmaxf(s_pm[w][2][o], s_pm[w][3][o]));
            outp[pbase * CH + o] = rv;
        }
        wave_fence();                                 // F4: WAR before next iter reuse
    }
}

extern "C" void kernel_launch(void* const* d_in, const int* in_sizes, int n_in,
                              void* d_out, int out_size, void* d_ws, size_t ws_size,
                              hipStream_t stream) {
    (void)in_sizes; (void)n_in; (void)out_size; (void)ws_size;
    const float* pts    = (const float*)d_in[0];
    const float* feat   = (const float*)d_in[1];
    const float* w_geom = (const float*)d_in[2];
    const float* g1     = (const float*)d_in[3];
    const float* b1     = (const float*)d_in[4];
    const float* m1     = (const float*)d_in[5];
    const float* v1     = (const float*)d_in[6];
    const float* w_sem  = (const float*)d_in[7];
    const float* g2     = (const float*)d_in[8];
    const float* b2     = (const float*)d_in[9];
    const float* m2     = (const float*)d_in[10];
    const float* v2     = (const float*)d_in[11];
    const float* w_fuse = (const float*)d_in[12];
    const float* g3     = (const float*)d_in[13];
    const float* b3     = (const float*)d_in[14];
    const float* m3     = (const float*)d_in[15];
    const float* v3     = (const float*)d_in[16];

    int*    idx_final = (int*)d_ws;                             // 2 MB @ 0
    uint4*  bfrag     = (uint4*)((char*)d_ws + (2ull << 20));   // 1 MB @ 2MB
    float4* pts4      = (float4*)((char*)d_ws + (4ull << 20));  // 512 KB @ 4MB

    pack_kernel<<<dim3(NB * NPTS / 256), dim3(256), 0, stream>>>(pts, pts4, bfrag);
    knn_mfma_kernel<<<dim3(NB * NPTS / 32), dim3(256), 0, stream>>>(pts4, bfrag, idx_final);

    agg_kernel<<<dim3(2048), dim3(256), 0, stream>>>(
        pts, feat, w_geom, g1, b1, m1, v1, w_sem, g2, b2, m2, v2,
        w_fuse, g3, b3, m3, v3, idx_final, (float*)d_out);
}